// Round 5
// baseline (5813.031 us; speedup 1.0000x reference)
//
#include <hip/hip_runtime.h>
#include <math.h>

// Problem constants (match reference)
#define NN 200000
#define EE 300000
#define BB 64
#define INV_SQRT_D 0.17677669529663687f

// ---- workspace layout in 4-byte words. Total ≈ 56.5M words = 226 MB.
// ws budget is ~256MB-class (252 passed, 329 faulted) -> stay <= 252 MB.
#define OFF_H    ((size_t)0)                    // [N][128] f32 node features
#define OFF_PQ   ((size_t)25600000)             // [N][64] uint (bf16x2): q, then v_base
#define OFF_PK   ((size_t)38400000)             // [N][64] uint (bf16x2): kt_r
#define OFF_S    ((size_t)51200000)             // [3][E][4] f32 scores -> alpha
#define OFF_RP   ((size_t)54800000)             // [3][N+1] int rowptr (padded 600016)
#define OFF_EIX  ((size_t)55400016)             // [3][E] int CSR edge index
#define OFF_WF   ((size_t)56300016)             // 10 x [128][128] f32 folded weights
#define OFF_BF   ((size_t)56463856)             // 10 x [128] f32 folded bias
#define OFF_BS   ((size_t)56465136)             // scan block sums 3*128 int
#define OFF_POOL ((size_t)56465520)             // psum [B][256] + pcnt [B][2]

#define SCAN_L   (NN + 1)
#define SCAN_E   8
#define SCAN_EPB (256 * SCAN_E)                          // 2048
#define SCAN_NB  ((SCAN_L + SCAN_EPB - 1) / SCAN_EPB)    // 98

__device__ __forceinline__ float gelu_exact(float v) {
    return 0.5f * v * (1.0f + erff(v * 0.70710678118654752f));
}
__device__ __forceinline__ float bflo(unsigned u) { return __uint_as_float(u << 16); }
__device__ __forceinline__ float bfhi(unsigned u) { return __uint_as_float(u & 0xffff0000u); }
__device__ __forceinline__ unsigned bfpack(float a, float b) {
    unsigned ua = __float_as_uint(a); ua += 0x7fffu + ((ua >> 16) & 1u);
    unsigned ub = __float_as_uint(b); ub += 0x7fffu + ((ub >> 16) & 1u);
    return (ua >> 16) | (ub & 0xffff0000u);
}

// ---- fold weights. 10 slots: per layer l: [l*5+0]=q copy, [l*5+1+r]=k@Wk_rel[r], [l*5+4]=v copy
__global__ __launch_bounds__(256) void fold_weights(
    const float* __restrict__ Wkqv, const float* __restrict__ bkqv,
    const float* __restrict__ Wk_rel,
    float* __restrict__ Wf, float* __restrict__ bf)
{
    __shared__ float Wr[4096];
    const int b = blockIdx.x, t = threadIdx.x;
    const int l = b / 5, s = b % 5;
    const float* Wq = Wkqv + (size_t)l * 49152;   // [128][384]
    if (s == 0 || s == 4) {
        const int off = (s == 0) ? 128 : 256;
        for (int i = t; i < 16384; i += 256) {
            int kk = i >> 7, c = i & 127;
            Wf[(size_t)b * 16384 + i] = Wq[kk * 384 + off + c];
        }
        if (t < 128) bf[b * 128 + t] = bkqv[l * 384 + off + t];
    } else {
        const int r = s - 1;
        const float* Wrel = Wk_rel + (size_t)(l * 3 + r) * 4096;
        for (int i = t; i < 4096; i += 256) Wr[i] = Wrel[i];
        __syncthreads();
        for (int i = t; i < 16384; i += 256) {
            int kk = i >> 7, c = i & 127, hh = c >> 5, f = c & 31;
            const float* wrow = Wq + kk * 384 + hh * 32;   // k block (cols 0..127)
            const float* wr = Wr + hh * 1024 + f;
            float sum = 0.f;
#pragma unroll
            for (int d = 0; d < 32; ++d) sum += wrow[d] * wr[d * 32];
            Wf[(size_t)b * 16384 + i] = sum;
        }
        if (t < 128) {
            int hh = t >> 5, f = t & 31;
            float sum = 0.f;
#pragma unroll
            for (int d = 0; d < 32; ++d)
                sum += bkqv[l * 384 + hh * 32 + d] * Wr[hh * 1024 + d * 32 + f];
            bf[b * 128 + t] = sum;
        }
    }
}

// ---------------- input projection: h = [emb[ast], x] @ Win + bin ----------------
__global__ __launch_bounds__(256) void input_proj(
    const float* __restrict__ x, const int* __restrict__ ast,
    const float* __restrict__ emb, const float* __restrict__ Win,
    const float* __restrict__ bin_, float* __restrict__ h)
{
    __shared__ float Ws[69 * 128];
    __shared__ float As[16 * 70];
    const int t = threadIdx.x;
    const int n0 = blockIdx.x * 16;
    for (int i = t; i < 69 * 128; i += 256) Ws[i] = Win[i];
    for (int i = t; i < 16 * 69; i += 256) {
        int nl = i / 69, kk = i - nl * 69;
        int n = n0 + nl;
        float v = (kk < 64) ? emb[ast[n] * 64 + kk] : x[n * 5 + (kk - 64)];
        As[nl * 70 + kk] = v;
    }
    __syncthreads();
    const int c = t & 127;
    const int nh = (t >> 7) * 8;
    float acc[8];
    float bv = bin_[c];
#pragma unroll
    for (int j = 0; j < 8; ++j) acc[j] = bv;
    for (int k = 0; k < 69; ++k) {
        float w = Ws[k * 128 + c];
#pragma unroll
        for (int j = 0; j < 8; ++j) acc[j] += As[(nh + j) * 70 + k] * w;
    }
#pragma unroll
    for (int j = 0; j < 8; ++j) h[(size_t)(n0 + nh + j) * 128 + c] = acc[j];
}

// ---- CSR build: histogram -> scan -> scatter ----
__global__ __launch_bounds__(256) void csr_hist(
    const int* __restrict__ ei0, const int* __restrict__ ei1, const int* __restrict__ ei2,
    int* __restrict__ rp)
{
    int idx = blockIdx.x * 256 + threadIdx.x;
    if (idx >= 3 * EE) return;
    int r = idx / EE, e = idx - r * EE;
    const int* ei = (r == 0) ? ei0 : ((r == 1) ? ei1 : ei2);
    atomicAdd(&rp[r * SCAN_L + ei[EE + e] + 1], 1);
}

__global__ __launch_bounds__(256) void scan1(int* __restrict__ rp, int* __restrict__ bs)
{
    __shared__ int ts[256];
    const int r = blockIdx.y;
    int* a = rp + (size_t)r * SCAN_L;
    const int base = blockIdx.x * SCAN_EPB + threadIdx.x * SCAN_E;
    int v[SCAN_E];
    int tot = 0;
#pragma unroll
    for (int j = 0; j < SCAN_E; ++j) {
        int idx = base + j;
        v[j] = (idx < SCAN_L) ? a[idx] : 0;
        tot += v[j];
    }
    ts[threadIdx.x] = tot;
    __syncthreads();
    for (int st = 1; st < 256; st <<= 1) {
        int add = (threadIdx.x >= st) ? ts[threadIdx.x - st] : 0;
        __syncthreads();
        ts[threadIdx.x] += add;
        __syncthreads();
    }
    int run = ts[threadIdx.x] - tot;
#pragma unroll
    for (int j = 0; j < SCAN_E; ++j) {
        run += v[j];
        int idx = base + j;
        if (idx < SCAN_L) a[idx] = run;
    }
    if (threadIdx.x == 255) bs[r * 128 + blockIdx.x] = ts[255];
}

__global__ __launch_bounds__(128) void scan2(int* __restrict__ bs)
{
    __shared__ int ts[128];
    const int r = blockIdx.x, t = threadIdx.x;
    int v = (t < SCAN_NB) ? bs[r * 128 + t] : 0;
    ts[t] = v;
    __syncthreads();
    for (int st = 1; st < 128; st <<= 1) {
        int add = (t >= st) ? ts[t - st] : 0;
        __syncthreads();
        ts[t] += add;
        __syncthreads();
    }
    bs[r * 128 + t] = ts[t];
}

__global__ __launch_bounds__(256) void scan3(int* __restrict__ rp, const int* __restrict__ bs)
{
    const int r = blockIdx.y;
    if (blockIdx.x == 0) return;
    const int off = bs[r * 128 + blockIdx.x - 1];
    const int base = blockIdx.x * SCAN_EPB + threadIdx.x * SCAN_E;
    int* a = rp + (size_t)r * SCAN_L;
#pragma unroll
    for (int j = 0; j < SCAN_E; ++j) {
        int idx = base + j;
        if (idx < SCAN_L) a[idx] += off;
    }
}

__global__ __launch_bounds__(256) void csr_scatter(
    const int* __restrict__ ei0, const int* __restrict__ ei1, const int* __restrict__ ei2,
    const int* __restrict__ rp, int* __restrict__ fill, int* __restrict__ eidx)
{
    int idx = blockIdx.x * 256 + threadIdx.x;
    if (idx >= 3 * EE) return;
    int r = idx / EE, e = idx - r * EE;
    const int* ei = (r == 0) ? ei0 : ((r == 1) ? ei1 : ei2);
    int dst = ei[EE + e];
    int pos = rp[r * SCAN_L + dst] + atomicAdd(&fill[r * NN + dst], 1);
    eidx[r * EE + pos] = e;
}

// ---- N x 128 @ 128 x 128 + bias -> bf16x2-packed plane [N][64] uint ----
__global__ __launch_bounds__(256) void gemm_bf(
    const float* __restrict__ in, const float* __restrict__ W,
    const float* __restrict__ bias, unsigned* __restrict__ outp)
{
    __shared__ float As[32 * 128];
    __shared__ float Ws[64 * 128];
    const int t = threadIdx.x;
    const int n0 = blockIdx.x * 32;
    for (int i = t; i < 32 * 32; i += 256) {
        int nl = i >> 5, k4 = i & 31;
        ((float4*)As)[nl * 32 + k4] = *(const float4*)(in + (size_t)(n0 + nl) * 128 + k4 * 4);
    }
    const int c = t & 63;                  // cols 2c, 2c+1
    const int ng = (t >> 6) * 8;
    float acc0[8], acc1[8];
    float b0 = bias[2 * c], b1 = bias[2 * c + 1];
#pragma unroll
    for (int j = 0; j < 8; ++j) { acc0[j] = b0; acc1[j] = b1; }
    for (int kc = 0; kc < 2; ++kc) {
        __syncthreads();
        for (int i = t; i < 64 * 32; i += 256) {
            int k = i >> 5, c4 = i & 31;
            ((float4*)Ws)[i] = *(const float4*)(W + (size_t)(kc * 64 + k) * 128 + c4 * 4);
        }
        __syncthreads();
        const float* Ab = As + kc * 64;
        for (int k = 0; k < 64; ++k) {
            float2 w = ((const float2*)Ws)[k * 64 + c];
#pragma unroll
            for (int j = 0; j < 8; ++j) {
                float a = Ab[(ng + j) * 128 + k];
                acc0[j] += a * w.x;
                acc1[j] += a * w.y;
            }
        }
    }
#pragma unroll
    for (int j = 0; j < 8; ++j)
        outp[(size_t)(n0 + ng + j) * 64 + c] = bfpack(acc0[j], acc1[j]);
}

// ---- edge scores, one relation, bf16 planes; thread = (edge, head) ----
__global__ __launch_bounds__(256) void edge_scores_rel(
    const unsigned* __restrict__ q_bf, const unsigned* __restrict__ k_bf,
    const int* __restrict__ ei, const float* __restrict__ p4,
    float* __restrict__ s, int r)
{
    int idx = blockIdx.x * 256 + threadIdx.x;
    if (idx >= EE * 4) return;
    int e = idx >> 2, hh = idx & 3;
    int src = ei[e], dst = ei[EE + e];
    const uint4* qp = (const uint4*)(q_bf + (size_t)dst * 64 + hh * 16);
    const uint4* kp = (const uint4*)(k_bf + (size_t)src * 64 + hh * 16);
    float sum = 0.f;
#pragma unroll
    for (int i = 0; i < 4; ++i) {
        uint4 qa = qp[i], ka = kp[i];
        sum += bflo(qa.x) * bflo(ka.x) + bfhi(qa.x) * bfhi(ka.x);
        sum += bflo(qa.y) * bflo(ka.y) + bfhi(qa.y) * bfhi(ka.y);
        sum += bflo(qa.z) * bflo(ka.z) + bfhi(qa.z) * bfhi(ka.z);
        sum += bflo(qa.w) * bflo(ka.w) + bfhi(qa.w) * bfhi(ka.w);
    }
    s[((size_t)r * EE + e) * 4 + hh] = sum * p4[hh] * INV_SQRT_D;
}

// ---- CSR segment softmax (one wave per dst; in-place s -> alpha) ----
__global__ __launch_bounds__(256) void csr_softmax(
    float* __restrict__ s, const int* __restrict__ rp, const int* __restrict__ eidx)
{
    const int dst = blockIdx.x * 4 + (threadIdx.x >> 6);
    const int lane = threadIdx.x & 63;
    const int sub = lane >> 2, hh = lane & 3;
    int beg[3], end[3];
#pragma unroll
    for (int r = 0; r < 3; ++r) {
        beg[r] = rp[r * SCAN_L + dst];
        end[r] = rp[r * SCAN_L + dst + 1];
    }
    float m = -INFINITY;
#pragma unroll
    for (int r = 0; r < 3; ++r)
        for (int p = beg[r] + sub; p < end[r]; p += 16) {
            int e = eidx[r * EE + p];
            m = fmaxf(m, s[((size_t)r * EE + e) * 4 + hh]);
        }
#pragma unroll
    for (int st = 4; st < 64; st <<= 1) m = fmaxf(m, __shfl_xor(m, st));
    float zz = 0.f;
#pragma unroll
    for (int r = 0; r < 3; ++r)
        for (int p = beg[r] + sub; p < end[r]; p += 16) {
            int e = eidx[r * EE + p];
            size_t off = ((size_t)r * EE + e) * 4 + hh;
            float ex = expf(s[off] - m);
            s[off] = ex;
            zz += ex;
        }
#pragma unroll
    for (int st = 4; st < 64; st <<= 1) zz += __shfl_xor(zz, st);
    float inv = 1.f / (zz + 1e-16f);
#pragma unroll
    for (int r = 0; r < 3; ++r)
        for (int p = beg[r] + sub; p < end[r]; p += 16) {
            int e = eidx[r * EE + p];
            s[((size_t)r * EE + e) * 4 + hh] *= inv;
        }
}

// ---- FUSED: per-relation aggregation of base v -> Wv_rel transform -> gelu
//             -> @Wout + bout -> skip gate -> LayerNorm -> h  (8 dsts/block)
// LDS plan (bytes):
//   stage 1/2: WrelB bf16 [3][2048] uints @0 (24576) | A f32 [8][3][132] @24576 (12672)
//              As f32 [8][128] @37248 (4096)
//   stage 3:   Ws f32 [64][128] @0 (32768, overlays WrelB+A) | As kept @37248
__global__ __launch_bounds__(256) void agg_out_ln(
    const unsigned* __restrict__ v_bf, const float* __restrict__ s,
    const int* __restrict__ rp, const int* __restrict__ eidx,
    const int* __restrict__ e0s, const int* __restrict__ e1s, const int* __restrict__ e2s,
    const float* __restrict__ Wv_rel,   // [3][4][32][32] for this layer
    const float* __restrict__ Wout, const float* __restrict__ bout,
    const float* __restrict__ skipp, const float* __restrict__ lg,
    const float* __restrict__ lb, float* __restrict__ h)
{
    __shared__ __align__(16) char smem[41344];
    unsigned* WrelB = (unsigned*)smem;            // 3*2048 uints
    float* A  = (float*)(smem + 24576);           // [8][3][132] padded (col + col/32)
    float* As = (float*)(smem + 37248);           // [8][128]
    float* Ws = (float*)smem;                     // stage-3 Wout chunk

    const int t = threadIdx.x;
    const int n0 = blockIdx.x * 8;

    for (int i = t; i < 3 * 2048; i += 256)
        WrelB[i] = bfpack(Wv_rel[2 * i], Wv_rel[2 * i + 1]);
    __syncthreads();

    // stage 1: aggregate base v per relation. wave w: dsts w*2, w*2+1.
    {
        const int w = t >> 6, lane = t & 63;
        const int col = 2 * lane;                 // cols col, col+1 (same head)
        const int hh = lane >> 4;
        const int pcol = col + (col >> 5);        // padded index (pitch 33/head)
        for (int i = 0; i < 2; ++i) {
            const int nl = w * 2 + i;
            const int dst = n0 + nl;
            for (int r = 0; r < 3; ++r) {
                const int* esrc = (r == 0) ? e0s : ((r == 1) ? e1s : e2s);
                const int beg = rp[r * SCAN_L + dst];
                const int end = rp[r * SCAN_L + dst + 1];
                float a0 = 0.f, a1 = 0.f;
                for (int p = beg; p < end; ++p) {
                    int e = eidx[r * EE + p];
                    int src = esrc[e];
                    float al = s[((size_t)r * EE + e) * 4 + hh];
                    unsigned v2 = v_bf[(size_t)src * 64 + lane];
                    a0 += al * bflo(v2);
                    a1 += al * bfhi(v2);
                }
                float* Ap = A + (nl * 3 + r) * 132 + pcol;
                Ap[0] = a0; Ap[1] = a1;
            }
        }
    }
    __syncthreads();

    // stage 2: out[nl][fh*32+f] = sum_r sum_d A[nl][r][fh*32+d] * Wrel[r][fh][d][f]; gelu -> As
    {
        const int tf = t & 31, nl = t >> 5;
        const int fh = tf >> 3, fq = tf & 7;       // cols fh*32 + fq*4 .. +3
        float o0 = 0.f, o1 = 0.f, o2 = 0.f, o3 = 0.f;
        for (int r = 0; r < 3; ++r) {
            const float* Arow = A + (nl * 3 + r) * 132 + fh * 33;
            const unsigned* Wp = WrelB + r * 2048 + fh * 512 + fq * 2;
#pragma unroll
            for (int d = 0; d < 32; ++d) {
                float a = Arow[d];
                unsigned w01 = Wp[d * 16];
                unsigned w23 = Wp[d * 16 + 1];
                o0 += a * bflo(w01); o1 += a * bfhi(w01);
                o2 += a * bflo(w23); o3 += a * bfhi(w23);
            }
        }
        float4 g = make_float4(gelu_exact(o0), gelu_exact(o1), gelu_exact(o2), gelu_exact(o3));
        *(float4*)(As + nl * 128 + fh * 32 + fq * 4) = g;
    }
    __syncthreads();

    // stage 3: As @ Wout + bout, skip, LN. thread: c = t&63 (cols c, c+64), rows rg, rg+1.
    const int c = t & 63;
    const int rg = (t >> 6) * 2;
    float acc0[2], acc1[2];
    float b0 = bout[c], b1 = bout[64 + c];
    acc0[0] = acc0[1] = b0; acc1[0] = acc1[1] = b1;
    for (int kc = 0; kc < 2; ++kc) {
        __syncthreads();
        for (int i = t; i < 64 * 32; i += 256) {
            int k = i >> 5, c4 = i & 31;
            ((float4*)Ws)[i] = *(const float4*)(Wout + (size_t)(kc * 64 + k) * 128 + c4 * 4);
        }
        __syncthreads();
        for (int k = 0; k < 64; ++k) {
            float w0 = Ws[k * 128 + c];
            float w1 = Ws[k * 128 + 64 + c];
#pragma unroll
            for (int i = 0; i < 2; ++i) {
                float a = As[(rg + i) * 128 + kc * 64 + k];
                acc0[i] += a * w0;
                acc1[i] += a * w1;
            }
        }
    }
    const float alpha = 1.f / (1.f + expf(-skipp[0]));
    const float om = 1.f - alpha;
    const float g0 = lg[c], g1 = lg[64 + c], lb0 = lb[c], lb1 = lb[64 + c];
#pragma unroll
    for (int i = 0; i < 2; ++i) {
        const size_t n = (size_t)(n0 + rg + i);
        float o0 = alpha * acc0[i] + om * h[n * 128 + c];
        float o1 = alpha * acc1[i] + om * h[n * 128 + 64 + c];
        float sm = o0 + o1;
#pragma unroll
        for (int m = 1; m < 64; m <<= 1) sm += __shfl_xor(sm, m);
        float mu = sm * (1.f / 128.f);
        float d0 = o0 - mu, d1 = o1 - mu;
        float sq = d0 * d0 + d1 * d1;
#pragma unroll
        for (int m = 1; m < 64; m <<= 1) sq += __shfl_xor(sq, m);
        float rs = rsqrtf(sq * (1.f / 128.f) + 1e-5f);
        h[n * 128 + c]      = d0 * rs * g0 + lb0;
        h[n * 128 + 64 + c] = d1 * rs * g1 + lb1;
    }
}

// ---- parallel masked mean-pool partials (batch sorted -> run-flush) ----
__global__ __launch_bounds__(256) void pool_partial(
    const float* __restrict__ h, const float* __restrict__ x,
    const int* __restrict__ batch, float* __restrict__ psum, float* __restrict__ pcnt)
{
    const int c = threadIdx.x & 127;
    const int n0 = blockIdx.x * 64 + (threadIdx.x >> 7) * 32;
    int g = batch[n0];
    float sw = 0.f, sn = 0.f, cw = 0.f, cn = 0.f;
    for (int i = 0; i < 32; ++i) {
        int n = n0 + i;
        int gn = batch[n];
        if (gn != g) {
            atomicAdd(&psum[g * 256 + c], sw);
            atomicAdd(&psum[g * 256 + 128 + c], sn);
            if (c == 0) { atomicAdd(&pcnt[g * 2], cw); atomicAdd(&pcnt[g * 2 + 1], cn); }
            sw = sn = cw = cn = 0.f;
            g = gn;
        }
        float w = (x[(size_t)n * 5 + 1] > 0.f) ? 1.f : 0.f;
        float hv = h[(size_t)n * 128 + c];
        sw += w * hv; sn += (1.f - w) * hv;
        cw += w; cn += 1.f - w;
    }
    atomicAdd(&psum[g * 256 + c], sw);
    atomicAdd(&psum[g * 256 + 128 + c], sn);
    if (c == 0) { atomicAdd(&pcnt[g * 2], cw); atomicAdd(&pcnt[g * 2 + 1], cn); }
}

// ---------------- MLP head (pool finalize fused) ----------------
__global__ __launch_bounds__(256) void head_kernel(
    const float* __restrict__ psum, const float* __restrict__ pcnt,
    const float* __restrict__ task,
    const float* __restrict__ Wtf, const float* __restrict__ btf,
    const float* __restrict__ Wc1, const float* __restrict__ bc1,
    const float* __restrict__ Wc2, const float* __restrict__ bc2,
    float* __restrict__ out)
{
    __shared__ float in_s[640];
    __shared__ float ge_s[256];
    __shared__ float hc_s[64];
    const int b = blockIdx.x, t = threadIdx.x;
    if (t < 256) {
        float cnt = pcnt[b * 2 + (t >> 7)];
        float sv = psum[b * 256 + t];
        in_s[t] = (cnt > 0.f) ? sv / fmaxf(cnt, 1.f) : 0.f;
    }
    for (int i = t; i < 384; i += 256) in_s[256 + i] = task[b * 384 + i];
    __syncthreads();
    float acc = btf[t];
    for (int i = 0; i < 640; ++i) acc += in_s[i] * Wtf[i * 256 + t];
    ge_s[t] = fmaxf(acc, 0.f);
    __syncthreads();
    if (t < 64) {
        float a2 = bc1[t];
        for (int i = 0; i < 256; ++i) a2 += ge_s[i] * Wc1[i * 64 + t];
        hc_s[t] = fmaxf(a2, 0.f);
    }
    __syncthreads();
    if (t < 64) {
        float v = hc_s[t] * Wc2[t];
#pragma unroll
        for (int off = 32; off >= 1; off >>= 1) v += __shfl_down(v, off);
        if (t == 0) out[b] = v + bc2[0];
    }
}

__global__ __launch_bounds__(256) void zero_kernel(float4* __restrict__ p, int count4)
{
    int i = blockIdx.x * 256 + threadIdx.x;
    if (i < count4) p[i] = make_float4(0.f, 0.f, 0.f, 0.f);
}

extern "C" void kernel_launch(void* const* d_in, const int* in_sizes, int n_in,
                              void* d_out, int out_size, void* d_ws, size_t ws_size,
                              hipStream_t stream)
{
    const float* x      = (const float*)d_in[0];
    const int*   ast    = (const int*)d_in[1];
    const int*   batch  = (const int*)d_in[2];
    const int*   ei[3]  = {(const int*)d_in[3], (const int*)d_in[4], (const int*)d_in[5]};
    const float* task   = (const float*)d_in[6];
    const float* emb    = (const float*)d_in[7];
    const float* Win    = (const float*)d_in[8];
    const float* bin_   = (const float*)d_in[9];
    const float* Wkqv   = (const float*)d_in[10];
    const float* bkqv   = (const float*)d_in[11];
    const float* Wk_rel = (const float*)d_in[12];
    const float* Wv_rel = (const float*)d_in[13];
    const float* p_rel  = (const float*)d_in[14];
    const float* Wout   = (const float*)d_in[15];
    const float* bout   = (const float*)d_in[16];
    const float* skip   = (const float*)d_in[17];
    const float* ln_g   = (const float*)d_in[18];
    const float* ln_b   = (const float*)d_in[19];
    const float* Wtf    = (const float*)d_in[20];
    const float* btf    = (const float*)d_in[21];
    const float* Wc1    = (const float*)d_in[22];
    const float* bc1    = (const float*)d_in[23];
    const float* Wc2    = (const float*)d_in[24];
    const float* bc2    = (const float*)d_in[25];
    float* out = (float*)d_out;
    float* ws  = (float*)d_ws;

    float*    h    = ws + OFF_H;
    unsigned* PQ   = (unsigned*)(ws + OFF_PQ);   // q plane, then v_base plane
    unsigned* PK   = (unsigned*)(ws + OFF_PK);   // kt_r plane
    float*    sbuf = ws + OFF_S;
    int*      rp   = (int*)(ws + OFF_RP);
    int*      eidx = (int*)(ws + OFF_EIX);
    int*      fill = (int*)(ws + OFF_PQ);        // aliases PQ during CSR build only
    float*    Wf   = ws + OFF_WF;
    float*    bf   = ws + OFF_BF;
    int*      bs   = (int*)(ws + OFF_BS);
    float*    psum = ws + OFF_POOL;
    float*    pcnt = psum + (size_t)BB * 256;

    fold_weights<<<10, 256, 0, stream>>>(Wkqv, bkqv, Wk_rel, Wf, bf);
    input_proj<<<NN / 16, 256, 0, stream>>>(x, ast, emb, Win, bin_, h);

    zero_kernel<<<(600016 / 4 + 255) / 256, 256, 0, stream>>>((float4*)rp, 600016 / 4);
    zero_kernel<<<(600000 / 4 + 255) / 256, 256, 0, stream>>>((float4*)fill, 600000 / 4);
    csr_hist<<<(3 * EE + 255) / 256, 256, 0, stream>>>(ei[0], ei[1], ei[2], rp);
    scan1<<<dim3(SCAN_NB, 3), 256, 0, stream>>>(rp, bs);
    scan2<<<3, 128, 0, stream>>>(bs);
    scan3<<<dim3(SCAN_NB, 3), 256, 0, stream>>>(rp, bs);
    csr_scatter<<<(3 * EE + 255) / 256, 256, 0, stream>>>(ei[0], ei[1], ei[2], rp, fill, eidx);

    for (int l = 0; l < 2; ++l) {
        const size_t ls = (size_t)l * 5;   // slots: 0=q, 1..3=k_r, 4=v
        gemm_bf<<<NN / 32, 256, 0, stream>>>(h, Wf + ls * 16384, bf + ls * 128, PQ);
        for (int r = 0; r < 3; ++r) {
            gemm_bf<<<NN / 32, 256, 0, stream>>>(
                h, Wf + (ls + 1 + r) * 16384, bf + (ls + 1 + r) * 128, PK);
            edge_scores_rel<<<(EE * 4 + 255) / 256, 256, 0, stream>>>(
                PQ, PK, ei[r], p_rel + (size_t)(l * 3 + r) * 4, sbuf, r);
        }
        csr_softmax<<<NN / 4, 256, 0, stream>>>(sbuf, rp, eidx);
        // q dead -> PQ becomes v_base
        gemm_bf<<<NN / 32, 256, 0, stream>>>(h, Wf + (ls + 4) * 16384, bf + (ls + 4) * 128, PQ);
        agg_out_ln<<<NN / 8, 256, 0, stream>>>(
            PQ, sbuf, rp, eidx, ei[0], ei[1], ei[2],
            Wv_rel + (size_t)l * 12288,
            Wout + (size_t)l * 16384, bout + (size_t)l * 128,
            skip + l, ln_g + (size_t)l * 128, ln_b + (size_t)l * 128, h);
    }

    zero_kernel<<<(16512 / 4 + 255) / 256, 256, 0, stream>>>((float4*)psum, 16512 / 4);
    pool_partial<<<NN / 64, 256, 0, stream>>>(h, x, batch, psum, pcnt);
    head_kernel<<<BB, 256, 0, stream>>>(psum, pcnt, task, Wtf, btf, Wc1, bc1, Wc2, bc2, out);
}

// Round 6
// 4215.038 us; speedup vs baseline: 1.3791x; 1.3791x over previous
//
#include <hip/hip_runtime.h>
#include <math.h>

// Problem constants (match reference)
#define NN 200000
#define EE 300000
#define BB 64
#define INV_SQRT_D 0.17677669529663687f

// ---- workspace layout in 4-byte words. Total ≈ 57.4M words = 229.5 MB.
// ws budget is ~256MB-class (252 passed, 329 faulted) -> stay <= 252 MB.
#define OFF_H    ((size_t)0)                    // [N][128] f32 node features
#define OFF_PQ   ((size_t)25600000)             // [N][64] uint (bf16x2): q, then v_base
#define OFF_PK   ((size_t)38400000)             // [N][64] uint (bf16x2): kt_r
#define OFF_S    ((size_t)51200000)             // [3][E][4] f32 scores -> alpha (CSR order!)
#define OFF_RP   ((size_t)54800000)             // [3][N+1] int rowptr (padded 600016)
#define OFF_CSRC ((size_t)55400016)             // [3][E] int src per CSR position
#define OFF_CDST ((size_t)56300016)             // [3][E] int dst per CSR position
#define OFF_WF   ((size_t)57200016)             // 10 x [128][128] f32 folded weights
#define OFF_BF   ((size_t)57363856)             // 10 x [128] f32 folded bias
#define OFF_BS   ((size_t)57365136)             // scan block sums 3*128 int
#define OFF_POOL ((size_t)57365520)             // psum [B][256] + pcnt [B][2]

#define SCAN_L   (NN + 1)
#define SCAN_E   8
#define SCAN_EPB (256 * SCAN_E)                          // 2048
#define SCAN_NB  ((SCAN_L + SCAN_EPB - 1) / SCAN_EPB)    // 98

__device__ __forceinline__ float gelu_exact(float v) {
    return 0.5f * v * (1.0f + erff(v * 0.70710678118654752f));
}
__device__ __forceinline__ float bflo(unsigned u) { return __uint_as_float(u << 16); }
__device__ __forceinline__ float bfhi(unsigned u) { return __uint_as_float(u & 0xffff0000u); }
__device__ __forceinline__ unsigned bfpack(float a, float b) {
    unsigned ua = __float_as_uint(a); ua += 0x7fffu + ((ua >> 16) & 1u);
    unsigned ub = __float_as_uint(b); ub += 0x7fffu + ((ub >> 16) & 1u);
    return (ua >> 16) | (ub & 0xffff0000u);
}

// ---- fold weights. 10 slots per call: per layer l: [l*5+0]=q copy, [l*5+1+r]=k@Wk_rel[r], [l*5+4]=v copy
__global__ __launch_bounds__(256) void fold_weights(
    const float* __restrict__ Wkqv, const float* __restrict__ bkqv,
    const float* __restrict__ Wk_rel,
    float* __restrict__ Wf, float* __restrict__ bf)
{
    __shared__ float Wr[4096];
    const int b = blockIdx.x, t = threadIdx.x;
    const int l = b / 5, s = b % 5;
    const float* Wq = Wkqv + (size_t)l * 49152;   // [128][384]
    if (s == 0 || s == 4) {
        const int off = (s == 0) ? 128 : 256;
        for (int i = t; i < 16384; i += 256) {
            int kk = i >> 7, c = i & 127;
            Wf[(size_t)b * 16384 + i] = Wq[kk * 384 + off + c];
        }
        if (t < 128) bf[b * 128 + t] = bkqv[l * 384 + off + t];
    } else {
        const int r = s - 1;
        const float* Wrel = Wk_rel + (size_t)(l * 3 + r) * 4096;
        for (int i = t; i < 4096; i += 256) Wr[i] = Wrel[i];
        __syncthreads();
        for (int i = t; i < 16384; i += 256) {
            int kk = i >> 7, c = i & 127, hh = c >> 5, f = c & 31;
            const float* wrow = Wq + kk * 384 + hh * 32;   // k block (cols 0..127)
            const float* wr = Wr + hh * 1024 + f;
            float sum = 0.f;
#pragma unroll
            for (int d = 0; d < 32; ++d) sum += wrow[d] * wr[d * 32];
            Wf[(size_t)b * 16384 + i] = sum;
        }
        if (t < 128) {
            int hh = t >> 5, f = t & 31;
            float sum = 0.f;
#pragma unroll
            for (int d = 0; d < 32; ++d)
                sum += bkqv[l * 384 + hh * 32 + d] * Wr[hh * 1024 + d * 32 + f];
            bf[b * 128 + t] = sum;
        }
    }
}

// ---------------- input projection: h = [emb[ast], x] @ Win + bin ----------------
__global__ __launch_bounds__(256) void input_proj(
    const float* __restrict__ x, const int* __restrict__ ast,
    const float* __restrict__ emb, const float* __restrict__ Win,
    const float* __restrict__ bin_, float* __restrict__ h)
{
    __shared__ float Ws[69 * 128];
    __shared__ float As[16 * 70];
    const int t = threadIdx.x;
    const int n0 = blockIdx.x * 16;
    for (int i = t; i < 69 * 128; i += 256) Ws[i] = Win[i];
    for (int i = t; i < 16 * 69; i += 256) {
        int nl = i / 69, kk = i - nl * 69;
        int n = n0 + nl;
        float v = (kk < 64) ? emb[ast[n] * 64 + kk] : x[n * 5 + (kk - 64)];
        As[nl * 70 + kk] = v;
    }
    __syncthreads();
    const int c = t & 127;
    const int nh = (t >> 7) * 8;
    float acc[8];
    float bv = bin_[c];
#pragma unroll
    for (int j = 0; j < 8; ++j) acc[j] = bv;
    for (int k = 0; k < 69; ++k) {
        float w = Ws[k * 128 + c];
#pragma unroll
        for (int j = 0; j < 8; ++j) acc[j] += As[(nh + j) * 70 + k] * w;
    }
#pragma unroll
    for (int j = 0; j < 8; ++j) h[(size_t)(n0 + nh + j) * 128 + c] = acc[j];
}

// ---- CSR build: histogram -> scan -> scatter (src+dst materialized per position) ----
__global__ __launch_bounds__(256) void csr_hist(
    const int* __restrict__ ei0, const int* __restrict__ ei1, const int* __restrict__ ei2,
    int* __restrict__ rp)
{
    int idx = blockIdx.x * 256 + threadIdx.x;
    if (idx >= 3 * EE) return;
    int r = idx / EE, e = idx - r * EE;
    const int* ei = (r == 0) ? ei0 : ((r == 1) ? ei1 : ei2);
    atomicAdd(&rp[r * SCAN_L + ei[EE + e] + 1], 1);
}

__global__ __launch_bounds__(256) void scan1(int* __restrict__ rp, int* __restrict__ bs)
{
    __shared__ int ts[256];
    const int r = blockIdx.y;
    int* a = rp + (size_t)r * SCAN_L;
    const int base = blockIdx.x * SCAN_EPB + threadIdx.x * SCAN_E;
    int v[SCAN_E];
    int tot = 0;
#pragma unroll
    for (int j = 0; j < SCAN_E; ++j) {
        int idx = base + j;
        v[j] = (idx < SCAN_L) ? a[idx] : 0;
        tot += v[j];
    }
    ts[threadIdx.x] = tot;
    __syncthreads();
    for (int st = 1; st < 256; st <<= 1) {
        int add = (threadIdx.x >= st) ? ts[threadIdx.x - st] : 0;
        __syncthreads();
        ts[threadIdx.x] += add;
        __syncthreads();
    }
    int run = ts[threadIdx.x] - tot;
#pragma unroll
    for (int j = 0; j < SCAN_E; ++j) {
        run += v[j];
        int idx = base + j;
        if (idx < SCAN_L) a[idx] = run;
    }
    if (threadIdx.x == 255) bs[r * 128 + blockIdx.x] = ts[255];
}

__global__ __launch_bounds__(128) void scan2(int* __restrict__ bs)
{
    __shared__ int ts[128];
    const int r = blockIdx.x, t = threadIdx.x;
    int v = (t < SCAN_NB) ? bs[r * 128 + t] : 0;
    ts[t] = v;
    __syncthreads();
    for (int st = 1; st < 128; st <<= 1) {
        int add = (t >= st) ? ts[t - st] : 0;
        __syncthreads();
        ts[t] += add;
        __syncthreads();
    }
    bs[r * 128 + t] = ts[t];
}

__global__ __launch_bounds__(256) void scan3(int* __restrict__ rp, const int* __restrict__ bs)
{
    const int r = blockIdx.y;
    if (blockIdx.x == 0) return;
    const int off = bs[r * 128 + blockIdx.x - 1];
    const int base = blockIdx.x * SCAN_EPB + threadIdx.x * SCAN_E;
    int* a = rp + (size_t)r * SCAN_L;
#pragma unroll
    for (int j = 0; j < SCAN_E; ++j) {
        int idx = base + j;
        if (idx < SCAN_L) a[idx] += off;
    }
}

__global__ __launch_bounds__(256) void csr_scatter(
    const int* __restrict__ ei0, const int* __restrict__ ei1, const int* __restrict__ ei2,
    const int* __restrict__ rp, int* __restrict__ fill,
    int* __restrict__ csrc, int* __restrict__ cdst)
{
    int idx = blockIdx.x * 256 + threadIdx.x;
    if (idx >= 3 * EE) return;
    int r = idx / EE, e = idx - r * EE;
    const int* ei = (r == 0) ? ei0 : ((r == 1) ? ei1 : ei2);
    int src = ei[e], dst = ei[EE + e];
    int pos = rp[r * SCAN_L + dst] + atomicAdd(&fill[r * NN + dst], 1);
    csrc[r * EE + pos] = src;
    cdst[r * EE + pos] = dst;
}

// ---- N x 128 @ 128 x 128 + bias -> bf16x2-packed plane [N][64] uint ----
__global__ __launch_bounds__(256) void gemm_bf(
    const float* __restrict__ in, const float* __restrict__ W,
    const float* __restrict__ bias, unsigned* __restrict__ outp)
{
    __shared__ float As[32 * 128];
    __shared__ float Ws[64 * 128];
    const int t = threadIdx.x;
    const int n0 = blockIdx.x * 32;
    for (int i = t; i < 32 * 32; i += 256) {
        int nl = i >> 5, k4 = i & 31;
        ((float4*)As)[nl * 32 + k4] = *(const float4*)(in + (size_t)(n0 + nl) * 128 + k4 * 4);
    }
    const int c = t & 63;                  // cols 2c, 2c+1
    const int ng = (t >> 6) * 8;
    float acc0[8], acc1[8];
    float b0 = bias[2 * c], b1 = bias[2 * c + 1];
#pragma unroll
    for (int j = 0; j < 8; ++j) { acc0[j] = b0; acc1[j] = b1; }
    for (int kc = 0; kc < 2; ++kc) {
        __syncthreads();
        for (int i = t; i < 64 * 32; i += 256) {
            int k = i >> 5, c4 = i & 31;
            ((float4*)Ws)[i] = *(const float4*)(W + (size_t)(kc * 64 + k) * 128 + c4 * 4);
        }
        __syncthreads();
        const float* Ab = As + kc * 64;
        for (int k = 0; k < 64; ++k) {
            float2 w = ((const float2*)Ws)[k * 64 + c];
#pragma unroll
            for (int j = 0; j < 8; ++j) {
                float a = Ab[(ng + j) * 128 + k];
                acc0[j] += a * w.x;
                acc1[j] += a * w.y;
            }
        }
    }
#pragma unroll
    for (int j = 0; j < 8; ++j)
        outp[(size_t)(n0 + ng + j) * 64 + c] = bfpack(acc0[j], acc1[j]);
}

// ---- edge scores in CSR position order: csrc/cdst sequential, q nearly-sorted, k random ----
__global__ __launch_bounds__(256) void edge_scores_csr(
    const unsigned* __restrict__ q_bf, const unsigned* __restrict__ k_bf,
    const int* __restrict__ csrc, const int* __restrict__ cdst,
    const float* __restrict__ p4, float* __restrict__ s_out)
{
    int idx = blockIdx.x * 256 + threadIdx.x;
    if (idx >= EE * 4) return;
    int p = idx >> 2, hh = idx & 3;
    int src = csrc[p], dst = cdst[p];
    const uint4* qp = (const uint4*)(q_bf + (size_t)dst * 64 + hh * 16);
    const uint4* kp = (const uint4*)(k_bf + (size_t)src * 64 + hh * 16);
    float sum = 0.f;
#pragma unroll
    for (int i = 0; i < 4; ++i) {
        uint4 qa = qp[i], ka = kp[i];
        sum += bflo(qa.x) * bflo(ka.x) + bfhi(qa.x) * bfhi(ka.x);
        sum += bflo(qa.y) * bflo(ka.y) + bfhi(qa.y) * bfhi(ka.y);
        sum += bflo(qa.z) * bflo(ka.z) + bfhi(qa.z) * bfhi(ka.z);
        sum += bflo(qa.w) * bflo(ka.w) + bfhi(qa.w) * bfhi(ka.w);
    }
    s_out[(size_t)p * 4 + hh] = sum * p4[hh] * INV_SQRT_D;
}

// ---- CSR segment softmax: s is CSR-ordered -> fully coalesced, zero indirection ----
__global__ __launch_bounds__(256) void csr_softmax(
    float* __restrict__ s, const int* __restrict__ rp)
{
    const int dst = blockIdx.x * 4 + (threadIdx.x >> 6);
    const int lane = threadIdx.x & 63;
    const int sub = lane >> 2, hh = lane & 3;
    int beg[3], end[3];
#pragma unroll
    for (int r = 0; r < 3; ++r) {
        beg[r] = rp[r * SCAN_L + dst];
        end[r] = rp[r * SCAN_L + dst + 1];
    }
    float m = -INFINITY;
#pragma unroll
    for (int r = 0; r < 3; ++r)
        for (int p = beg[r] + sub; p < end[r]; p += 16)
            m = fmaxf(m, s[((size_t)r * EE + p) * 4 + hh]);
#pragma unroll
    for (int st = 4; st < 64; st <<= 1) m = fmaxf(m, __shfl_xor(m, st));
    float zz = 0.f;
#pragma unroll
    for (int r = 0; r < 3; ++r)
        for (int p = beg[r] + sub; p < end[r]; p += 16) {
            size_t off = ((size_t)r * EE + p) * 4 + hh;
            float ex = expf(s[off] - m);
            s[off] = ex;
            zz += ex;
        }
#pragma unroll
    for (int st = 4; st < 64; st <<= 1) zz += __shfl_xor(zz, st);
    float inv = 1.f / (zz + 1e-16f);
#pragma unroll
    for (int r = 0; r < 3; ++r)
        for (int p = beg[r] + sub; p < end[r]; p += 16)
            s[((size_t)r * EE + p) * 4 + hh] *= inv;
}

// ---- FUSED: CSR aggregation (1 dependent gather/edge) -> Wv_rel -> gelu -> Wout
//             -> skip -> LayerNorm -> h.  4 dsts/block, wave per dst.
// LDS: stage1/2: WrelB bf16 6144 uints @0 (24576) | A f32 [4][3][132] @24576 (6336)
//      stage3:   WoutB bf16 [128][64] @0 (32768, packs cols (c, c+64))
//      As f32 [4][128] @33024 (2048) survives both.  Total 35072 B.
__global__ __launch_bounds__(256) void agg_out_ln(
    const unsigned* __restrict__ v_bf, const float* __restrict__ s,
    const int* __restrict__ rp, const int* __restrict__ csrc,
    const float* __restrict__ Wv_rel,   // [3][4][32][32] this layer
    const float* __restrict__ Wout, const float* __restrict__ bout,
    const float* __restrict__ skipp, const float* __restrict__ lg,
    const float* __restrict__ lb, float* __restrict__ h)
{
    __shared__ __align__(16) char smem[35072];
    unsigned* WrelB = (unsigned*)smem;
    float*    A     = (float*)(smem + 24576);
    unsigned* WoutB = (unsigned*)smem;
    float*    As    = (float*)(smem + 33024);

    const int t = threadIdx.x;
    const int n0 = blockIdx.x * 4;
    const int w = t >> 6, lane = t & 63;
    const int hh = lane >> 4;
    const int dst = n0 + w;

    for (int i = t; i < 6144; i += 256)
        WrelB[i] = bfpack(Wv_rel[2 * i], Wv_rel[2 * i + 1]);

    // stage 1: aggregate base v; only v_bf is a dependent gather
    {
        const int col = 2 * lane;
        const int pcol = col + (col >> 5);      // padded pitch 33/head
        for (int r = 0; r < 3; ++r) {
            const int beg = rp[r * SCAN_L + dst];
            const int end = rp[r * SCAN_L + dst + 1];
            float a0 = 0.f, a1 = 0.f;
            int p = beg, src = 0; float al = 0.f;
            if (p < end) {
                src = csrc[r * EE + p];
                al  = s[((size_t)r * EE + p) * 4 + hh];
            }
            while (p < end) {
                unsigned v2 = v_bf[(size_t)src * 64 + lane];
                int p1 = p + 1, srcn = 0; float aln = 0.f;
                if (p1 < end) {                  // prefetch next edge's operands
                    srcn = csrc[r * EE + p1];
                    aln  = s[((size_t)r * EE + p1) * 4 + hh];
                }
                a0 += al * bflo(v2);
                a1 += al * bfhi(v2);
                p = p1; src = srcn; al = aln;
            }
            float* Ap = A + (w * 3 + r) * 132 + pcol;
            Ap[0] = a0; Ap[1] = a1;
        }
    }
    __syncthreads();

    // stage 2: per-head 32x32 Wv_rel transforms, sum over relations, gelu -> As
    {
        const int nl = t >> 6, tf = t & 63;
        const int fh = tf >> 4, fq = tf & 15;    // cols fh*32 + 2fq, +1
        float o0 = 0.f, o1 = 0.f;
        for (int r = 0; r < 3; ++r) {
            const float* Arow = A + (nl * 3 + r) * 132 + fh * 33;
            const unsigned* Wp = WrelB + (r * 4 + fh) * 512 + fq;
#pragma unroll
            for (int d = 0; d < 32; ++d) {
                float av = Arow[d];
                unsigned ww = Wp[d * 16];
                o0 += av * bflo(ww);
                o1 += av * bfhi(ww);
            }
        }
        As[nl * 128 + fh * 32 + 2 * fq]     = gelu_exact(o0);
        As[nl * 128 + fh * 32 + 2 * fq + 1] = gelu_exact(o1);
    }
    __syncthreads();

    // stage 3: Wout (bf16, packed (c, c+64)) + skip + LN
    for (int i = t; i < 128 * 64; i += 256) {
        int k = i >> 6, j = i & 63;
        WoutB[i] = bfpack(Wout[(size_t)k * 128 + j], Wout[(size_t)k * 128 + j + 64]);
    }
    __syncthreads();
    const int c = lane;          // cols c, c+64; row = w
    float acc0 = bout[c], acc1 = bout[64 + c];
    for (int k = 0; k < 128; ++k) {
        float a = As[w * 128 + k];           // broadcast
        unsigned w2 = WoutB[k * 64 + c];
        acc0 += a * bflo(w2);
        acc1 += a * bfhi(w2);
    }
    const float alpha = 1.f / (1.f + expf(-skipp[0]));
    const float om = 1.f - alpha;
    const size_t n = (size_t)dst;
    float o0 = alpha * acc0 + om * h[n * 128 + c];
    float o1 = alpha * acc1 + om * h[n * 128 + 64 + c];
    float sm = o0 + o1;
#pragma unroll
    for (int m = 1; m < 64; m <<= 1) sm += __shfl_xor(sm, m);
    float mu = sm * (1.f / 128.f);
    float d0 = o0 - mu, d1 = o1 - mu;
    float sq = d0 * d0 + d1 * d1;
#pragma unroll
    for (int m = 1; m < 64; m <<= 1) sq += __shfl_xor(sq, m);
    float rs = rsqrtf(sq * (1.f / 128.f) + 1e-5f);
    h[n * 128 + c]      = d0 * rs * lg[c]      + lb[c];
    h[n * 128 + 64 + c] = d1 * rs * lg[64 + c] + lb[64 + c];
}

// ---- parallel masked mean-pool partials (batch sorted -> run-flush) ----
__global__ __launch_bounds__(256) void pool_partial(
    const float* __restrict__ h, const float* __restrict__ x,
    const int* __restrict__ batch, float* __restrict__ psum, float* __restrict__ pcnt)
{
    const int c = threadIdx.x & 127;
    const int n0 = blockIdx.x * 64 + (threadIdx.x >> 7) * 32;
    int g = batch[n0];
    float sw = 0.f, sn = 0.f, cw = 0.f, cn = 0.f;
    for (int i = 0; i < 32; ++i) {
        int n = n0 + i;
        int gn = batch[n];
        if (gn != g) {
            atomicAdd(&psum[g * 256 + c], sw);
            atomicAdd(&psum[g * 256 + 128 + c], sn);
            if (c == 0) { atomicAdd(&pcnt[g * 2], cw); atomicAdd(&pcnt[g * 2 + 1], cn); }
            sw = sn = cw = cn = 0.f;
            g = gn;
        }
        float w = (x[(size_t)n * 5 + 1] > 0.f) ? 1.f : 0.f;
        float hv = h[(size_t)n * 128 + c];
        sw += w * hv; sn += (1.f - w) * hv;
        cw += w; cn += 1.f - w;
    }
    atomicAdd(&psum[g * 256 + c], sw);
    atomicAdd(&psum[g * 256 + 128 + c], sn);
    if (c == 0) { atomicAdd(&pcnt[g * 2], cw); atomicAdd(&pcnt[g * 2 + 1], cn); }
}

// ---------------- MLP head (pool finalize fused) ----------------
__global__ __launch_bounds__(256) void head_kernel(
    const float* __restrict__ psum, const float* __restrict__ pcnt,
    const float* __restrict__ task,
    const float* __restrict__ Wtf, const float* __restrict__ btf,
    const float* __restrict__ Wc1, const float* __restrict__ bc1,
    const float* __restrict__ Wc2, const float* __restrict__ bc2,
    float* __restrict__ out)
{
    __shared__ float in_s[640];
    __shared__ float ge_s[256];
    __shared__ float hc_s[64];
    const int b = blockIdx.x, t = threadIdx.x;
    if (t < 256) {
        float cnt = pcnt[b * 2 + (t >> 7)];
        float sv = psum[b * 256 + t];
        in_s[t] = (cnt > 0.f) ? sv / fmaxf(cnt, 1.f) : 0.f;
    }
    for (int i = t; i < 384; i += 256) in_s[256 + i] = task[b * 384 + i];
    __syncthreads();
    float acc = btf[t];
    for (int i = 0; i < 640; ++i) acc += in_s[i] * Wtf[i * 256 + t];
    ge_s[t] = fmaxf(acc, 0.f);
    __syncthreads();
    if (t < 64) {
        float a2 = bc1[t];
        for (int i = 0; i < 256; ++i) a2 += ge_s[i] * Wc1[i * 64 + t];
        hc_s[t] = fmaxf(a2, 0.f);
    }
    __syncthreads();
    if (t < 64) {
        float v = hc_s[t] * Wc2[t];
#pragma unroll
        for (int off = 32; off >= 1; off >>= 1) v += __shfl_down(v, off);
        if (t == 0) out[b] = v + bc2[0];
    }
}

__global__ __launch_bounds__(256) void zero_kernel(float4* __restrict__ p, int count4)
{
    int i = blockIdx.x * 256 + threadIdx.x;
    if (i < count4) p[i] = make_float4(0.f, 0.f, 0.f, 0.f);
}

extern "C" void kernel_launch(void* const* d_in, const int* in_sizes, int n_in,
                              void* d_out, int out_size, void* d_ws, size_t ws_size,
                              hipStream_t stream)
{
    const float* x      = (const float*)d_in[0];
    const int*   ast    = (const int*)d_in[1];
    const int*   batch  = (const int*)d_in[2];
    const int*   ei[3]  = {(const int*)d_in[3], (const int*)d_in[4], (const int*)d_in[5]};
    const float* task   = (const float*)d_in[6];
    const float* emb    = (const float*)d_in[7];
    const float* Win    = (const float*)d_in[8];
    const float* bin_   = (const float*)d_in[9];
    const float* Wkqv   = (const float*)d_in[10];
    const float* bkqv   = (const float*)d_in[11];
    const float* Wk_rel = (const float*)d_in[12];
    const float* Wv_rel = (const float*)d_in[13];
    const float* p_rel  = (const float*)d_in[14];
    const float* Wout   = (const float*)d_in[15];
    const float* bout   = (const float*)d_in[16];
    const float* skip   = (const float*)d_in[17];
    const float* ln_g   = (const float*)d_in[18];
    const float* ln_b   = (const float*)d_in[19];
    const float* Wtf    = (const float*)d_in[20];
    const float* btf    = (const float*)d_in[21];
    const float* Wc1    = (const float*)d_in[22];
    const float* bc1    = (const float*)d_in[23];
    const float* Wc2    = (const float*)d_in[24];
    const float* bc2    = (const float*)d_in[25];
    float* out = (float*)d_out;
    float* ws  = (float*)d_ws;

    float*    h    = ws + OFF_H;
    unsigned* PQ   = (unsigned*)(ws + OFF_PQ);   // q plane, then v_base plane
    unsigned* PK   = (unsigned*)(ws + OFF_PK);   // kt_r plane
    float*    sbuf = ws + OFF_S;
    int*      rp   = (int*)(ws + OFF_RP);
    int*      csrc = (int*)(ws + OFF_CSRC);
    int*      cdst = (int*)(ws + OFF_CDST);
    int*      fill = (int*)(ws + OFF_PQ);        // aliases PQ during CSR build only
    float*    Wf   = ws + OFF_WF;
    float*    bf   = ws + OFF_BF;
    int*      bs   = (int*)(ws + OFF_BS);
    float*    psum = ws + OFF_POOL;
    float*    pcnt = psum + (size_t)BB * 256;

    fold_weights<<<10, 256, 0, stream>>>(Wkqv, bkqv, Wk_rel, Wf, bf);
    input_proj<<<NN / 16, 256, 0, stream>>>(x, ast, emb, Win, bin_, h);

    zero_kernel<<<(600016 / 4 + 255) / 256, 256, 0, stream>>>((float4*)rp, 600016 / 4);
    zero_kernel<<<(600000 / 4 + 255) / 256, 256, 0, stream>>>((float4*)fill, 600000 / 4);
    csr_hist<<<(3 * EE + 255) / 256, 256, 0, stream>>>(ei[0], ei[1], ei[2], rp);
    scan1<<<dim3(SCAN_NB, 3), 256, 0, stream>>>(rp, bs);
    scan2<<<3, 128, 0, stream>>>(bs);
    scan3<<<dim3(SCAN_NB, 3), 256, 0, stream>>>(rp, bs);
    csr_scatter<<<(3 * EE + 255) / 256, 256, 0, stream>>>(
        ei[0], ei[1], ei[2], rp, fill, csrc, cdst);

    for (int l = 0; l < 2; ++l) {
        const size_t ls = (size_t)l * 5;   // slots: 0=q, 1..3=k_r, 4=v
        gemm_bf<<<NN / 32, 256, 0, stream>>>(h, Wf + ls * 16384, bf + ls * 128, PQ);
        for (int r = 0; r < 3; ++r) {
            gemm_bf<<<NN / 32, 256, 0, stream>>>(
                h, Wf + (ls + 1 + r) * 16384, bf + (ls + 1 + r) * 128, PK);
            edge_scores_csr<<<(EE * 4 + 255) / 256, 256, 0, stream>>>(
                PQ, PK, csrc + (size_t)r * EE, cdst + (size_t)r * EE,
                p_rel + (size_t)(l * 3 + r) * 4, sbuf + (size_t)r * EE * 4);
        }
        csr_softmax<<<NN / 4, 256, 0, stream>>>(sbuf, rp);
        // q dead -> PQ becomes v_base
        gemm_bf<<<NN / 32, 256, 0, stream>>>(h, Wf + (ls + 4) * 16384, bf + (ls + 4) * 128, PQ);
        agg_out_ln<<<NN / 4, 256, 0, stream>>>(
            PQ, sbuf, rp, csrc,
            Wv_rel + (size_t)l * 12288,
            Wout + (size_t)l * 16384, bout + (size_t)l * 128,
            skip + l, ln_g + (size_t)l * 128, ln_b + (size_t)l * 128, h);
    }

    zero_kernel<<<(16512 / 4 + 255) / 256, 256, 0, stream>>>((float4*)psum, 16512 / 4);
    pool_partial<<<NN / 64, 256, 0, stream>>>(h, x, batch, psum, pcnt);
    head_kernel<<<BB, 256, 0, stream>>>(psum, pcnt, task, Wtf, btf, Wc1, bc1, Wc2, bc2, out);
}

// Round 7
// 4210.622 us; speedup vs baseline: 1.3806x; 1.0010x over previous
//
#include <hip/hip_runtime.h>
#include <math.h>

// Problem constants (match reference)
#define NN 200000
#define EE 300000
#define BB 64
#define INV_SQRT_D 0.17677669529663687f

// ---- workspace layout in 4-byte words. Total ≈ 57.4M words = 229.6 MB.
// ws budget is ~256MB-class (252 passed, 329 faulted) -> stay <= 252 MB.
#define OFF_H    ((size_t)0)                    // [N][128] f32 node features
#define OFF_PQ   ((size_t)25600000)             // [N][64] uint (bf16x2): q, then v_base
#define OFF_PK   ((size_t)38400000)             // [N][64] uint (bf16x2): kt_r, then As plane
#define OFF_S    ((size_t)51200000)             // [3][E][4] f32 scores -> alpha (CSR order)
#define OFF_RP   ((size_t)54800000)             // [3][N+1] int rowptr (padded 600016)
#define OFF_CSRC ((size_t)55400016)             // [3][E] int src per CSR position
#define OFF_CDST ((size_t)56300016)             // [3][E] int dst per CSR position
#define OFF_WF   ((size_t)57200016)             // 10 x [128][128] f32 folded weights
#define OFF_BF   ((size_t)57363856)             // 10 x [128] f32 folded bias
#define OFF_BS   ((size_t)57365136)             // scan block sums 3*128 int
#define OFF_POOL ((size_t)57365520)             // psum [B][256] + pcnt [B][2] (16512)
#define OFF_WVB  ((size_t)57382032)             // 2 x 6144 uint packed Wv_rel

#define SCAN_L   (NN + 1)
#define SCAN_E   8
#define SCAN_EPB (256 * SCAN_E)                          // 2048
#define SCAN_NB  ((SCAN_L + SCAN_EPB - 1) / SCAN_EPB)    // 98

__device__ __forceinline__ float gelu_exact(float v) {
    return 0.5f * v * (1.0f + erff(v * 0.70710678118654752f));
}
__device__ __forceinline__ float bflo(unsigned u) { return __uint_as_float(u << 16); }
__device__ __forceinline__ float bfhi(unsigned u) { return __uint_as_float(u & 0xffff0000u); }
__device__ __forceinline__ unsigned bfpack(float a, float b) {
    unsigned ua = __float_as_uint(a); ua += 0x7fffu + ((ua >> 16) & 1u);
    unsigned ub = __float_as_uint(b); ub += 0x7fffu + ((ub >> 16) & 1u);
    return (ua >> 16) | (ub & 0xffff0000u);
}

// ---- fold weights. 10 slots: per layer l: [l*5+0]=q copy, [l*5+1+r]=k@Wk_rel[r], [l*5+4]=v copy
__global__ __launch_bounds__(256) void fold_weights(
    const float* __restrict__ Wkqv, const float* __restrict__ bkqv,
    const float* __restrict__ Wk_rel,
    float* __restrict__ Wf, float* __restrict__ bf)
{
    __shared__ float Wr[4096];
    const int b = blockIdx.x, t = threadIdx.x;
    const int l = b / 5, s = b % 5;
    const float* Wq = Wkqv + (size_t)l * 49152;   // [128][384]
    if (s == 0 || s == 4) {
        const int off = (s == 0) ? 128 : 256;
        for (int i = t; i < 16384; i += 256) {
            int kk = i >> 7, c = i & 127;
            Wf[(size_t)b * 16384 + i] = Wq[kk * 384 + off + c];
        }
        if (t < 128) bf[b * 128 + t] = bkqv[l * 384 + off + t];
    } else {
        const int r = s - 1;
        const float* Wrel = Wk_rel + (size_t)(l * 3 + r) * 4096;
        for (int i = t; i < 4096; i += 256) Wr[i] = Wrel[i];
        __syncthreads();
        for (int i = t; i < 16384; i += 256) {
            int kk = i >> 7, c = i & 127, hh = c >> 5, f = c & 31;
            const float* wrow = Wq + kk * 384 + hh * 32;   // k block (cols 0..127)
            const float* wr = Wr + hh * 1024 + f;
            float sum = 0.f;
#pragma unroll
            for (int d = 0; d < 32; ++d) sum += wrow[d] * wr[d * 32];
            Wf[(size_t)b * 16384 + i] = sum;
        }
        if (t < 128) {
            int hh = t >> 5, f = t & 31;
            float sum = 0.f;
#pragma unroll
            for (int d = 0; d < 32; ++d)
                sum += bkqv[l * 384 + hh * 32 + d] * Wr[hh * 1024 + d * 32 + f];
            bf[b * 128 + t] = sum;
        }
    }
}

// ---- pack Wv_rel (both layers) to bf16x2 once per call ----
__global__ __launch_bounds__(256) void pack_wv(
    const float* __restrict__ Wv_rel, unsigned* __restrict__ WvB)
{
    int i = blockIdx.x * 256 + threadIdx.x;
    if (i < 12288) WvB[i] = bfpack(Wv_rel[2 * i], Wv_rel[2 * i + 1]);
}

// ---------------- input projection: h = [emb[ast], x] @ Win + bin ----------------
__global__ __launch_bounds__(256) void input_proj(
    const float* __restrict__ x, const int* __restrict__ ast,
    const float* __restrict__ emb, const float* __restrict__ Win,
    const float* __restrict__ bin_, float* __restrict__ h)
{
    __shared__ float Ws[69 * 128];
    __shared__ float As[16 * 70];
    const int t = threadIdx.x;
    const int n0 = blockIdx.x * 16;
    for (int i = t; i < 69 * 128; i += 256) Ws[i] = Win[i];
    for (int i = t; i < 16 * 69; i += 256) {
        int nl = i / 69, kk = i - nl * 69;
        int n = n0 + nl;
        float v = (kk < 64) ? emb[ast[n] * 64 + kk] : x[n * 5 + (kk - 64)];
        As[nl * 70 + kk] = v;
    }
    __syncthreads();
    const int c = t & 127;
    const int nh = (t >> 7) * 8;
    float acc[8];
    float bv = bin_[c];
#pragma unroll
    for (int j = 0; j < 8; ++j) acc[j] = bv;
    for (int k = 0; k < 69; ++k) {
        float w = Ws[k * 128 + c];
#pragma unroll
        for (int j = 0; j < 8; ++j) acc[j] += As[(nh + j) * 70 + k] * w;
    }
#pragma unroll
    for (int j = 0; j < 8; ++j) h[(size_t)(n0 + nh + j) * 128 + c] = acc[j];
}

// ---- CSR build: histogram -> scan -> scatter ----
__global__ __launch_bounds__(256) void csr_hist(
    const int* __restrict__ ei0, const int* __restrict__ ei1, const int* __restrict__ ei2,
    int* __restrict__ rp)
{
    int idx = blockIdx.x * 256 + threadIdx.x;
    if (idx >= 3 * EE) return;
    int r = idx / EE, e = idx - r * EE;
    const int* ei = (r == 0) ? ei0 : ((r == 1) ? ei1 : ei2);
    atomicAdd(&rp[r * SCAN_L + ei[EE + e] + 1], 1);
}

__global__ __launch_bounds__(256) void scan1(int* __restrict__ rp, int* __restrict__ bs)
{
    __shared__ int ts[256];
    const int r = blockIdx.y;
    int* a = rp + (size_t)r * SCAN_L;
    const int base = blockIdx.x * SCAN_EPB + threadIdx.x * SCAN_E;
    int v[SCAN_E];
    int tot = 0;
#pragma unroll
    for (int j = 0; j < SCAN_E; ++j) {
        int idx = base + j;
        v[j] = (idx < SCAN_L) ? a[idx] : 0;
        tot += v[j];
    }
    ts[threadIdx.x] = tot;
    __syncthreads();
    for (int st = 1; st < 256; st <<= 1) {
        int add = (threadIdx.x >= st) ? ts[threadIdx.x - st] : 0;
        __syncthreads();
        ts[threadIdx.x] += add;
        __syncthreads();
    }
    int run = ts[threadIdx.x] - tot;
#pragma unroll
    for (int j = 0; j < SCAN_E; ++j) {
        run += v[j];
        int idx = base + j;
        if (idx < SCAN_L) a[idx] = run;
    }
    if (threadIdx.x == 255) bs[r * 128 + blockIdx.x] = ts[255];
}

__global__ __launch_bounds__(128) void scan2(int* __restrict__ bs)
{
    __shared__ int ts[128];
    const int r = blockIdx.x, t = threadIdx.x;
    int v = (t < SCAN_NB) ? bs[r * 128 + t] : 0;
    ts[t] = v;
    __syncthreads();
    for (int st = 1; st < 128; st <<= 1) {
        int add = (t >= st) ? ts[t - st] : 0;
        __syncthreads();
        ts[t] += add;
        __syncthreads();
    }
    bs[r * 128 + t] = ts[t];
}

__global__ __launch_bounds__(256) void scan3(int* __restrict__ rp, const int* __restrict__ bs)
{
    const int r = blockIdx.y;
    if (blockIdx.x == 0) return;
    const int off = bs[r * 128 + blockIdx.x - 1];
    const int base = blockIdx.x * SCAN_EPB + threadIdx.x * SCAN_E;
    int* a = rp + (size_t)r * SCAN_L;
#pragma unroll
    for (int j = 0; j < SCAN_E; ++j) {
        int idx = base + j;
        if (idx < SCAN_L) a[idx] += off;
    }
}

__global__ __launch_bounds__(256) void csr_scatter(
    const int* __restrict__ ei0, const int* __restrict__ ei1, const int* __restrict__ ei2,
    const int* __restrict__ rp, int* __restrict__ fill,
    int* __restrict__ csrc, int* __restrict__ cdst)
{
    int idx = blockIdx.x * 256 + threadIdx.x;
    if (idx >= 3 * EE) return;
    int r = idx / EE, e = idx - r * EE;
    const int* ei = (r == 0) ? ei0 : ((r == 1) ? ei1 : ei2);
    int src = ei[e], dst = ei[EE + e];
    int pos = rp[r * SCAN_L + dst] + atomicAdd(&fill[r * NN + dst], 1);
    csrc[r * EE + pos] = src;
    cdst[r * EE + pos] = dst;
}

// ---- N x 128 @ 128 x 128 + bias -> bf16x2 plane [N][64] uint. 4x4 register tile. ----
__global__ __launch_bounds__(256) void gemm_bf(
    const float* __restrict__ in, const float* __restrict__ W,
    const float* __restrict__ bias, unsigned* __restrict__ outp)
{
    __shared__ float As[32 * 128];    // 16 KB
    __shared__ float Ws[64 * 128];    // 32 KB (K chunked by 64)
    const int t = threadIdx.x;
    const int n0 = blockIdx.x * 32;
    for (int i = t; i < 32 * 32; i += 256) {
        int nl = i >> 5, k4 = i & 31;
        ((float4*)As)[nl * 32 + k4] = *(const float4*)(in + (size_t)(n0 + nl) * 128 + k4 * 4);
    }
    const int cg = t & 31;            // cols 4cg .. 4cg+3
    const int rg = (t >> 5) * 4;      // rows rg .. rg+3
    float4 bv = *(const float4*)(bias + 4 * cg);
    float acc[4][4];
#pragma unroll
    for (int i = 0; i < 4; ++i) {
        acc[i][0] = bv.x; acc[i][1] = bv.y; acc[i][2] = bv.z; acc[i][3] = bv.w;
    }
    for (int kc = 0; kc < 2; ++kc) {
        __syncthreads();
        for (int i = t; i < 64 * 32; i += 256) {
            int k = i >> 5, c4 = i & 31;
            ((float4*)Ws)[i] = *(const float4*)(W + (size_t)(kc * 64 + k) * 128 + c4 * 4);
        }
        __syncthreads();
        const float* Ab = As + kc * 64;
        for (int k = 0; k < 64; ++k) {
            float4 w = ((const float4*)Ws)[k * 32 + cg];
#pragma unroll
            for (int i = 0; i < 4; ++i) {
                float a = Ab[(rg + i) * 128 + k];
                acc[i][0] += a * w.x; acc[i][1] += a * w.y;
                acc[i][2] += a * w.z; acc[i][3] += a * w.w;
            }
        }
    }
#pragma unroll
    for (int i = 0; i < 4; ++i) {
        uint2 u = make_uint2(bfpack(acc[i][0], acc[i][1]), bfpack(acc[i][2], acc[i][3]));
        *(uint2*)(outp + (size_t)(n0 + rg + i) * 64 + 2 * cg) = u;
    }
}

// ---- edge scores in CSR position order ----
__global__ __launch_bounds__(256) void edge_scores_csr(
    const unsigned* __restrict__ q_bf, const unsigned* __restrict__ k_bf,
    const int* __restrict__ csrc, const int* __restrict__ cdst,
    const float* __restrict__ p4, float* __restrict__ s_out)
{
    int idx = blockIdx.x * 256 + threadIdx.x;
    if (idx >= EE * 4) return;
    int p = idx >> 2, hh = idx & 3;
    int src = csrc[p], dst = cdst[p];
    const uint4* qp = (const uint4*)(q_bf + (size_t)dst * 64 + hh * 16);
    const uint4* kp = (const uint4*)(k_bf + (size_t)src * 64 + hh * 16);
    float sum = 0.f;
#pragma unroll
    for (int i = 0; i < 4; ++i) {
        uint4 qa = qp[i], ka = kp[i];
        sum += bflo(qa.x) * bflo(ka.x) + bfhi(qa.x) * bfhi(ka.x);
        sum += bflo(qa.y) * bflo(ka.y) + bfhi(qa.y) * bfhi(ka.y);
        sum += bflo(qa.z) * bflo(ka.z) + bfhi(qa.z) * bfhi(ka.z);
        sum += bflo(qa.w) * bflo(ka.w) + bfhi(qa.w) * bfhi(ka.w);
    }
    s_out[(size_t)p * 4 + hh] = sum * p4[hh] * INV_SQRT_D;
}

// ---- CSR segment softmax (coalesced, zero indirection) ----
__global__ __launch_bounds__(256) void csr_softmax(
    float* __restrict__ s, const int* __restrict__ rp)
{
    const int dst = blockIdx.x * 4 + (threadIdx.x >> 6);
    const int lane = threadIdx.x & 63;
    const int sub = lane >> 2, hh = lane & 3;
    int beg[3], end[3];
#pragma unroll
    for (int r = 0; r < 3; ++r) {
        beg[r] = rp[r * SCAN_L + dst];
        end[r] = rp[r * SCAN_L + dst + 1];
    }
    float m = -INFINITY;
#pragma unroll
    for (int r = 0; r < 3; ++r)
        for (int p = beg[r] + sub; p < end[r]; p += 16)
            m = fmaxf(m, s[((size_t)r * EE + p) * 4 + hh]);
#pragma unroll
    for (int st = 4; st < 64; st <<= 1) m = fmaxf(m, __shfl_xor(m, st));
    float zz = 0.f;
#pragma unroll
    for (int r = 0; r < 3; ++r)
        for (int p = beg[r] + sub; p < end[r]; p += 16) {
            size_t off = ((size_t)r * EE + p) * 4 + hh;
            float ex = expf(s[off] - m);
            s[off] = ex;
            zz += ex;
        }
#pragma unroll
    for (int st = 4; st < 64; st <<= 1) zz += __shfl_xor(zz, st);
    float inv = 1.f / (zz + 1e-16f);
#pragma unroll
    for (int r = 0; r < 3; ++r)
        for (int p = beg[r] + sub; p < end[r]; p += 16)
            s[((size_t)r * EE + p) * 4 + hh] *= inv;
}

// ---- agg_v: edge-parallel CSR aggregation (LDS f32 atomics) + Wv_rel + gelu -> As bf16
// 8 dsts/block. LDS: WrelB (12 mats, padded pitch 528) 25344B | A [8][3][132] f32 12672B.
__global__ __launch_bounds__(256) void agg_v(
    const unsigned* __restrict__ v_bf, const float* __restrict__ s,
    const int* __restrict__ rp, const int* __restrict__ csrc,
    const int* __restrict__ cdst,
    const unsigned* __restrict__ WvB,    // packed [3][4][32][16] this layer
    unsigned* __restrict__ As_g)
{
    __shared__ __align__(16) char smem[38016];
    unsigned* WrelB = (unsigned*)smem;             // 12 * 528
    float*    A     = (float*)(smem + 25344);      // [8][3][132]

    const int t = threadIdx.x;
    const int n0 = blockIdx.x * 8;
    const int w = t >> 6, lane = t & 63;

    for (int i = t; i < 6144; i += 256) {
        int mat = i >> 9, off = i & 511;
        WrelB[mat * 528 + off] = WvB[i];
    }
    for (int i = t; i < 8 * 3 * 132; i += 256) A[i] = 0.f;
    __syncthreads();

    // stage 1: edge-parallel, positions strided across waves; independent iterations
    {
        const int hh = lane >> 4;
        const int pcol = 2 * lane + hh;            // padded col (pitch 33/head)
        for (int r = 0; r < 3; ++r) {
            const int rb = rp[r * SCAN_L + n0];
            const int re = rp[r * SCAN_L + n0 + 8];
            for (int p = rb + w; p < re; p += 4) {
                int src = csrc[r * EE + p];
                int dl  = cdst[r * EE + p] - n0;
                float al = s[((size_t)r * EE + p) * 4 + hh];
                unsigned v2 = v_bf[(size_t)src * 64 + lane];
                float* Ap = A + (dl * 3 + r) * 132 + pcol;
                atomicAdd(Ap,     al * bflo(v2));
                atomicAdd(Ap + 1, al * bfhi(v2));
            }
        }
    }
    __syncthreads();

    // stage 2: per-head 32x32 transforms, sum over r, gelu, pack -> As_g
    {
        const int pi = t & 63, fh = pi >> 4, fq = pi & 15;
        const int rg = (t >> 6) * 2;               // rows rg, rg+1
        float o00 = 0.f, o01 = 0.f, o10 = 0.f, o11 = 0.f;
        for (int r = 0; r < 3; ++r) {
            const float* A0 = A + (rg * 3 + r) * 132 + fh * 33;
            const float* A1 = A0 + 3 * 132;
            const unsigned* Wp = WrelB + (r * 4 + fh) * 528 + fq;
#pragma unroll
            for (int d = 0; d < 32; ++d) {
                unsigned ww = Wp[d * 16];
                float w0 = bflo(ww), w1 = bfhi(ww);
                float a0 = A0[d], a1 = A1[d];
                o00 += a0 * w0; o01 += a0 * w1;
                o10 += a1 * w0; o11 += a1 * w1;
            }
        }
        As_g[(size_t)(n0 + rg) * 64 + fh * 16 + fq] =
            bfpack(gelu_exact(o00), gelu_exact(o01));
        As_g[(size_t)(n0 + rg + 1) * 64 + fh * 16 + fq] =
            bfpack(gelu_exact(o10), gelu_exact(o11));
    }
}

// ---- out_ln: As(bf16) @ Wout + bout -> skip -> LayerNorm -> h. 32 rows/block, 4x4 tile ----
__global__ __launch_bounds__(256) void out_ln(
    const unsigned* __restrict__ As_g, float* __restrict__ h,
    const float* __restrict__ Wout, const float* __restrict__ bout,
    const float* __restrict__ skipp, const float* __restrict__ lg,
    const float* __restrict__ lb)
{
    __shared__ float Asl[32 * 130];   // 16640 B (padded pitch 130)
    __shared__ float Ws[64 * 128];    // 32768 B
    const int t = threadIdx.x;
    const int n0 = blockIdx.x * 32;
    for (int i = t; i < 32 * 64; i += 256) {
        int row = i >> 6, j = i & 63;
        unsigned u = As_g[(size_t)(n0 + row) * 64 + j];
        Asl[row * 130 + 2 * j]     = bflo(u);
        Asl[row * 130 + 2 * j + 1] = bfhi(u);
    }
    const int cg = t & 31;            // cols 4cg..4cg+3
    const int rg = (t >> 5) * 4;      // rows rg..rg+3
    float4 bv = *(const float4*)(bout + 4 * cg);
    float acc[4][4];
#pragma unroll
    for (int i = 0; i < 4; ++i) {
        acc[i][0] = bv.x; acc[i][1] = bv.y; acc[i][2] = bv.z; acc[i][3] = bv.w;
    }
    for (int kc = 0; kc < 2; ++kc) {
        __syncthreads();
        for (int i = t; i < 64 * 32; i += 256) {
            int k = i >> 5, c4 = i & 31;
            ((float4*)Ws)[i] = *(const float4*)(Wout + (size_t)(kc * 64 + k) * 128 + c4 * 4);
        }
        __syncthreads();
        for (int k = 0; k < 64; ++k) {
            float4 w = ((const float4*)Ws)[k * 32 + cg];
#pragma unroll
            for (int i = 0; i < 4; ++i) {
                float a = Asl[(rg + i) * 130 + kc * 64 + k];
                acc[i][0] += a * w.x; acc[i][1] += a * w.y;
                acc[i][2] += a * w.z; acc[i][3] += a * w.w;
            }
        }
    }
    const float alpha = 1.f / (1.f + expf(-skipp[0]));
    const float om = 1.f - alpha;
    float4 g4 = *(const float4*)(lg + 4 * cg);
    float4 b4 = *(const float4*)(lb + 4 * cg);
#pragma unroll
    for (int i = 0; i < 4; ++i) {
        const size_t n = (size_t)(n0 + rg + i);
        float4 hv = *(const float4*)(h + n * 128 + 4 * cg);
        float o0 = alpha * acc[i][0] + om * hv.x;
        float o1 = alpha * acc[i][1] + om * hv.y;
        float o2 = alpha * acc[i][2] + om * hv.z;
        float o3 = alpha * acc[i][3] + om * hv.w;
        float sm = o0 + o1 + o2 + o3;
#pragma unroll
        for (int m = 1; m < 32; m <<= 1) sm += __shfl_xor(sm, m);
        float mu = sm * (1.f / 128.f);
        float d0 = o0 - mu, d1 = o1 - mu, d2 = o2 - mu, d3 = o3 - mu;
        float sq = d0 * d0 + d1 * d1 + d2 * d2 + d3 * d3;
#pragma unroll
        for (int m = 1; m < 32; m <<= 1) sq += __shfl_xor(sq, m);
        float rs = rsqrtf(sq * (1.f / 128.f) + 1e-5f);
        float4 o = make_float4(d0 * rs * g4.x + b4.x, d1 * rs * g4.y + b4.y,
                               d2 * rs * g4.z + b4.z, d3 * rs * g4.w + b4.w);
        *(float4*)(h + n * 128 + 4 * cg) = o;
    }
}

// ---- parallel masked mean-pool partials (batch sorted -> run-flush) ----
__global__ __launch_bounds__(256) void pool_partial(
    const float* __restrict__ h, const float* __restrict__ x,
    const int* __restrict__ batch, float* __restrict__ psum, float* __restrict__ pcnt)
{
    const int c = threadIdx.x & 127;
    const int n0 = blockIdx.x * 64 + (threadIdx.x >> 7) * 32;
    int g = batch[n0];
    float sw = 0.f, sn = 0.f, cw = 0.f, cn = 0.f;
    for (int i = 0; i < 32; ++i) {
        int n = n0 + i;
        int gn = batch[n];
        if (gn != g) {
            atomicAdd(&psum[g * 256 + c], sw);
            atomicAdd(&psum[g * 256 + 128 + c], sn);
            if (c == 0) { atomicAdd(&pcnt[g * 2], cw); atomicAdd(&pcnt[g * 2 + 1], cn); }
            sw = sn = cw = cn = 0.f;
            g = gn;
        }
        float w = (x[(size_t)n * 5 + 1] > 0.f) ? 1.f : 0.f;
        float hv = h[(size_t)n * 128 + c];
        sw += w * hv; sn += (1.f - w) * hv;
        cw += w; cn += 1.f - w;
    }
    atomicAdd(&psum[g * 256 + c], sw);
    atomicAdd(&psum[g * 256 + 128 + c], sn);
    if (c == 0) { atomicAdd(&pcnt[g * 2], cw); atomicAdd(&pcnt[g * 2 + 1], cn); }
}

// ---------------- MLP head (pool finalize fused) ----------------
__global__ __launch_bounds__(256) void head_kernel(
    const float* __restrict__ psum, const float* __restrict__ pcnt,
    const float* __restrict__ task,
    const float* __restrict__ Wtf, const float* __restrict__ btf,
    const float* __restrict__ Wc1, const float* __restrict__ bc1,
    const float* __restrict__ Wc2, const float* __restrict__ bc2,
    float* __restrict__ out)
{
    __shared__ float in_s[640];
    __shared__ float ge_s[256];
    __shared__ float hc_s[64];
    const int b = blockIdx.x, t = threadIdx.x;
    if (t < 256) {
        float cnt = pcnt[b * 2 + (t >> 7)];
        float sv = psum[b * 256 + t];
        in_s[t] = (cnt > 0.f) ? sv / fmaxf(cnt, 1.f) : 0.f;
    }
    for (int i = t; i < 384; i += 256) in_s[256 + i] = task[b * 384 + i];
    __syncthreads();
    float acc = btf[t];
    for (int i = 0; i < 640; ++i) acc += in_s[i] * Wtf[i * 256 + t];
    ge_s[t] = fmaxf(acc, 0.f);
    __syncthreads();
    if (t < 64) {
        float a2 = bc1[t];
        for (int i = 0; i < 256; ++i) a2 += ge_s[i] * Wc1[i * 64 + t];
        hc_s[t] = fmaxf(a2, 0.f);
    }
    __syncthreads();
    if (t < 64) {
        float v = hc_s[t] * Wc2[t];
#pragma unroll
        for (int off = 32; off >= 1; off >>= 1) v += __shfl_down(v, off);
        if (t == 0) out[b] = v + bc2[0];
    }
}

__global__ __launch_bounds__(256) void zero_kernel(float4* __restrict__ p, int count4)
{
    int i = blockIdx.x * 256 + threadIdx.x;
    if (i < count4) p[i] = make_float4(0.f, 0.f, 0.f, 0.f);
}

extern "C" void kernel_launch(void* const* d_in, const int* in_sizes, int n_in,
                              void* d_out, int out_size, void* d_ws, size_t ws_size,
                              hipStream_t stream)
{
    const float* x      = (const float*)d_in[0];
    const int*   ast    = (const int*)d_in[1];
    const int*   batch  = (const int*)d_in[2];
    const int*   ei[3]  = {(const int*)d_in[3], (const int*)d_in[4], (const int*)d_in[5]};
    const float* task   = (const float*)d_in[6];
    const float* emb    = (const float*)d_in[7];
    const float* Win    = (const float*)d_in[8];
    const float* bin_   = (const float*)d_in[9];
    const float* Wkqv   = (const float*)d_in[10];
    const float* bkqv   = (const float*)d_in[11];
    const float* Wk_rel = (const float*)d_in[12];
    const float* Wv_rel = (const float*)d_in[13];
    const float* p_rel  = (const float*)d_in[14];
    const float* Wout   = (const float*)d_in[15];
    const float* bout   = (const float*)d_in[16];
    const float* skip   = (const float*)d_in[17];
    const float* ln_g   = (const float*)d_in[18];
    const float* ln_b   = (const float*)d_in[19];
    const float* Wtf    = (const float*)d_in[20];
    const float* btf    = (const float*)d_in[21];
    const float* Wc1    = (const float*)d_in[22];
    const float* bc1    = (const float*)d_in[23];
    const float* Wc2    = (const float*)d_in[24];
    const float* bc2    = (const float*)d_in[25];
    float* out = (float*)d_out;
    float* ws  = (float*)d_ws;

    float*    h    = ws + OFF_H;
    unsigned* PQ   = (unsigned*)(ws + OFF_PQ);   // q plane, then v_base plane
    unsigned* PK   = (unsigned*)(ws + OFF_PK);   // kt_r plane, then As plane
    float*    sbuf = ws + OFF_S;
    int*      rp   = (int*)(ws + OFF_RP);
    int*      csrc = (int*)(ws + OFF_CSRC);
    int*      cdst = (int*)(ws + OFF_CDST);
    int*      fill = (int*)(ws + OFF_PQ);        // aliases PQ during CSR build only
    float*    Wf   = ws + OFF_WF;
    float*    bf   = ws + OFF_BF;
    int*      bs   = (int*)(ws + OFF_BS);
    float*    psum = ws + OFF_POOL;
    float*    pcnt = psum + (size_t)BB * 256;
    unsigned* WvB  = (unsigned*)(ws + OFF_WVB);

    fold_weights<<<10, 256, 0, stream>>>(Wkqv, bkqv, Wk_rel, Wf, bf);
    pack_wv<<<48, 256, 0, stream>>>(Wv_rel, WvB);
    input_proj<<<NN / 16, 256, 0, stream>>>(x, ast, emb, Win, bin_, h);

    zero_kernel<<<(600016 / 4 + 255) / 256, 256, 0, stream>>>((float4*)rp, 600016 / 4);
    zero_kernel<<<(600000 / 4 + 255) / 256, 256, 0, stream>>>((float4*)fill, 600000 / 4);
    csr_hist<<<(3 * EE + 255) / 256, 256, 0, stream>>>(ei[0], ei[1], ei[2], rp);
    scan1<<<dim3(SCAN_NB, 3), 256, 0, stream>>>(rp, bs);
    scan2<<<3, 128, 0, stream>>>(bs);
    scan3<<<dim3(SCAN_NB, 3), 256, 0, stream>>>(rp, bs);
    csr_scatter<<<(3 * EE + 255) / 256, 256, 0, stream>>>(
        ei[0], ei[1], ei[2], rp, fill, csrc, cdst);

    for (int l = 0; l < 2; ++l) {
        const size_t ls = (size_t)l * 5;   // slots: 0=q, 1..3=k_r, 4=v
        gemm_bf<<<NN / 32, 256, 0, stream>>>(h, Wf + ls * 16384, bf + ls * 128, PQ);
        for (int r = 0; r < 3; ++r) {
            gemm_bf<<<NN / 32, 256, 0, stream>>>(
                h, Wf + (ls + 1 + r) * 16384, bf + (ls + 1 + r) * 128, PK);
            edge_scores_csr<<<(EE * 4 + 255) / 256, 256, 0, stream>>>(
                PQ, PK, csrc + (size_t)r * EE, cdst + (size_t)r * EE,
                p_rel + (size_t)(l * 3 + r) * 4, sbuf + (size_t)r * EE * 4);
        }
        csr_softmax<<<NN / 4, 256, 0, stream>>>(sbuf, rp);
        // q dead -> PQ becomes v_base; kt dead -> PK becomes As plane
        gemm_bf<<<NN / 32, 256, 0, stream>>>(h, Wf + (ls + 4) * 16384, bf + (ls + 4) * 128, PQ);
        agg_v<<<NN / 8, 256, 0, stream>>>(
            PQ, sbuf, rp, csrc, cdst, WvB + (size_t)l * 6144, PK);
        out_ln<<<NN / 32, 256, 0, stream>>>(
            PK, h, Wout + (size_t)l * 16384, bout + (size_t)l * 128,
            skip + l, ln_g + (size_t)l * 128, ln_b + (size_t)l * 128);
    }

    zero_kernel<<<(16512 / 4 + 255) / 256, 256, 0, stream>>>((float4*)psum, 16512 / 4);
    pool_partial<<<NN / 64, 256, 0, stream>>>(h, x, batch, psum, pcnt);
    head_kernel<<<BB, 256, 0, stream>>>(psum, pcnt, task, Wtf, btf, Wc1, bc1, Wc2, bc2, out);
}

// Round 8
// 3497.714 us; speedup vs baseline: 1.6620x; 1.2038x over previous
//
#include <hip/hip_runtime.h>
#include <math.h>

// Problem constants (match reference)
#define NN 200000
#define EE 300000
#define BB 64
#define INV_SQRT_D 0.17677669529663687f

// ---- workspace layout in 4-byte words. Total ≈ 57.4M words = 229.6 MB.
// ws budget is ~256MB-class (252 passed, 329 faulted) -> stay <= 252 MB.
#define OFF_H    ((size_t)0)                    // [N][128] f32 node features
#define OFF_PQ   ((size_t)25600000)             // [N][64] uint (bf16x2): q, then v_base
#define OFF_PK   ((size_t)38400000)             // [N][64] uint (bf16x2): kt_r, then As plane
#define OFF_S    ((size_t)51200000)             // [3][E][4] f32 scores -> alpha (CSR order)
#define OFF_RP   ((size_t)54800000)             // [3][N+1] int rowptr (padded 600016)
#define OFF_CSRC ((size_t)55400016)             // [3][E] int src per CSR position
#define OFF_CDST ((size_t)56300016)             // [3][E] int dst per CSR position
#define OFF_WF   ((size_t)57200016)             // 10 x [128][128] f32 folded weights
#define OFF_BF   ((size_t)57363856)             // 10 x [128] f32 folded bias
#define OFF_BS   ((size_t)57365136)             // scan block sums 3*128 int
#define OFF_POOL ((size_t)57365520)             // psum [B][256] + pcnt [B][2] (16512)
#define OFF_WVB  ((size_t)57382032)             // 2 x 6144 uint packed Wv_rel

#define SCAN_L   (NN + 1)
#define SCAN_E   8
#define SCAN_EPB (256 * SCAN_E)                          // 2048
#define SCAN_NB  ((SCAN_L + SCAN_EPB - 1) / SCAN_EPB)    // 98

__device__ __forceinline__ float gelu_exact(float v) {
    return 0.5f * v * (1.0f + erff(v * 0.70710678118654752f));
}
__device__ __forceinline__ float bflo(unsigned u) { return __uint_as_float(u << 16); }
__device__ __forceinline__ float bfhi(unsigned u) { return __uint_as_float(u & 0xffff0000u); }
__device__ __forceinline__ unsigned bfpack(float a, float b) {
    unsigned ua = __float_as_uint(a); ua += 0x7fffu + ((ua >> 16) & 1u);
    unsigned ub = __float_as_uint(b); ub += 0x7fffu + ((ub >> 16) & 1u);
    return (ua >> 16) | (ub & 0xffff0000u);
}

// ---- fold weights. 10 slots: per layer l: [l*5+0]=q copy, [l*5+1+r]=k@Wk_rel[r], [l*5+4]=v copy
__global__ __launch_bounds__(256) void fold_weights(
    const float* __restrict__ Wkqv, const float* __restrict__ bkqv,
    const float* __restrict__ Wk_rel,
    float* __restrict__ Wf, float* __restrict__ bf)
{
    __shared__ float Wr[4096];
    const int b = blockIdx.x, t = threadIdx.x;
    const int l = b / 5, s = b % 5;
    const float* Wq = Wkqv + (size_t)l * 49152;   // [128][384]
    if (s == 0 || s == 4) {
        const int off = (s == 0) ? 128 : 256;
        for (int i = t; i < 16384; i += 256) {
            int kk = i >> 7, c = i & 127;
            Wf[(size_t)b * 16384 + i] = Wq[kk * 384 + off + c];
        }
        if (t < 128) bf[b * 128 + t] = bkqv[l * 384 + off + t];
    } else {
        const int r = s - 1;
        const float* Wrel = Wk_rel + (size_t)(l * 3 + r) * 4096;
        for (int i = t; i < 4096; i += 256) Wr[i] = Wrel[i];
        __syncthreads();
        for (int i = t; i < 16384; i += 256) {
            int kk = i >> 7, c = i & 127, hh = c >> 5, f = c & 31;
            const float* wrow = Wq + kk * 384 + hh * 32;   // k block (cols 0..127)
            const float* wr = Wr + hh * 1024 + f;
            float sum = 0.f;
#pragma unroll
            for (int d = 0; d < 32; ++d) sum += wrow[d] * wr[d * 32];
            Wf[(size_t)b * 16384 + i] = sum;
        }
        if (t < 128) {
            int hh = t >> 5, f = t & 31;
            float sum = 0.f;
#pragma unroll
            for (int d = 0; d < 32; ++d)
                sum += bkqv[l * 384 + hh * 32 + d] * Wr[hh * 1024 + d * 32 + f];
            bf[b * 128 + t] = sum;
        }
    }
}

// ---- pack Wv_rel (both layers) to bf16x2 once per call ----
__global__ __launch_bounds__(256) void pack_wv(
    const float* __restrict__ Wv_rel, unsigned* __restrict__ WvB)
{
    int i = blockIdx.x * 256 + threadIdx.x;
    if (i < 12288) WvB[i] = bfpack(Wv_rel[2 * i], Wv_rel[2 * i + 1]);
}

// ---------------- input projection: h = [emb[ast], x] @ Win + bin ----------------
__global__ __launch_bounds__(256) void input_proj(
    const float* __restrict__ x, const int* __restrict__ ast,
    const float* __restrict__ emb, const float* __restrict__ Win,
    const float* __restrict__ bin_, float* __restrict__ h)
{
    __shared__ float Ws[69 * 128];
    __shared__ float As[16 * 70];
    const int t = threadIdx.x;
    const int n0 = blockIdx.x * 16;
    for (int i = t; i < 69 * 128; i += 256) Ws[i] = Win[i];
    for (int i = t; i < 16 * 69; i += 256) {
        int nl = i / 69, kk = i - nl * 69;
        int n = n0 + nl;
        float v = (kk < 64) ? emb[ast[n] * 64 + kk] : x[n * 5 + (kk - 64)];
        As[nl * 70 + kk] = v;
    }
    __syncthreads();
    const int c = t & 127;
    const int nh = (t >> 7) * 8;
    float acc[8];
    float bv = bin_[c];
#pragma unroll
    for (int j = 0; j < 8; ++j) acc[j] = bv;
    for (int k = 0; k < 69; ++k) {
        float w = Ws[k * 128 + c];
#pragma unroll
        for (int j = 0; j < 8; ++j) acc[j] += As[(nh + j) * 70 + k] * w;
    }
#pragma unroll
    for (int j = 0; j < 8; ++j) h[(size_t)(n0 + nh + j) * 128 + c] = acc[j];
}

// ---- CSR build: histogram -> scan -> scatter ----
__global__ __launch_bounds__(256) void csr_hist(
    const int* __restrict__ ei0, const int* __restrict__ ei1, const int* __restrict__ ei2,
    int* __restrict__ rp)
{
    int idx = blockIdx.x * 256 + threadIdx.x;
    if (idx >= 3 * EE) return;
    int r = idx / EE, e = idx - r * EE;
    const int* ei = (r == 0) ? ei0 : ((r == 1) ? ei1 : ei2);
    atomicAdd(&rp[r * SCAN_L + ei[EE + e] + 1], 1);
}

__global__ __launch_bounds__(256) void scan1(int* __restrict__ rp, int* __restrict__ bs)
{
    __shared__ int ts[256];
    const int r = blockIdx.y;
    int* a = rp + (size_t)r * SCAN_L;
    const int base = blockIdx.x * SCAN_EPB + threadIdx.x * SCAN_E;
    int v[SCAN_E];
    int tot = 0;
#pragma unroll
    for (int j = 0; j < SCAN_E; ++j) {
        int idx = base + j;
        v[j] = (idx < SCAN_L) ? a[idx] : 0;
        tot += v[j];
    }
    ts[threadIdx.x] = tot;
    __syncthreads();
    for (int st = 1; st < 256; st <<= 1) {
        int add = (threadIdx.x >= st) ? ts[threadIdx.x - st] : 0;
        __syncthreads();
        ts[threadIdx.x] += add;
        __syncthreads();
    }
    int run = ts[threadIdx.x] - tot;
#pragma unroll
    for (int j = 0; j < SCAN_E; ++j) {
        run += v[j];
        int idx = base + j;
        if (idx < SCAN_L) a[idx] = run;
    }
    if (threadIdx.x == 255) bs[r * 128 + blockIdx.x] = ts[255];
}

__global__ __launch_bounds__(128) void scan2(int* __restrict__ bs)
{
    __shared__ int ts[128];
    const int r = blockIdx.x, t = threadIdx.x;
    int v = (t < SCAN_NB) ? bs[r * 128 + t] : 0;
    ts[t] = v;
    __syncthreads();
    for (int st = 1; st < 128; st <<= 1) {
        int add = (t >= st) ? ts[t - st] : 0;
        __syncthreads();
        ts[t] += add;
        __syncthreads();
    }
    bs[r * 128 + t] = ts[t];
}

__global__ __launch_bounds__(256) void scan3(int* __restrict__ rp, const int* __restrict__ bs)
{
    const int r = blockIdx.y;
    if (blockIdx.x == 0) return;
    const int off = bs[r * 128 + blockIdx.x - 1];
    const int base = blockIdx.x * SCAN_EPB + threadIdx.x * SCAN_E;
    int* a = rp + (size_t)r * SCAN_L;
#pragma unroll
    for (int j = 0; j < SCAN_E; ++j) {
        int idx = base + j;
        if (idx < SCAN_L) a[idx] += off;
    }
}

__global__ __launch_bounds__(256) void csr_scatter(
    const int* __restrict__ ei0, const int* __restrict__ ei1, const int* __restrict__ ei2,
    const int* __restrict__ rp, int* __restrict__ fill,
    int* __restrict__ csrc, int* __restrict__ cdst)
{
    int idx = blockIdx.x * 256 + threadIdx.x;
    if (idx >= 3 * EE) return;
    int r = idx / EE, e = idx - r * EE;
    const int* ei = (r == 0) ? ei0 : ((r == 1) ? ei1 : ei2);
    int src = ei[e], dst = ei[EE + e];
    int pos = rp[r * SCAN_L + dst] + atomicAdd(&fill[r * NN + dst], 1);
    csrc[r * EE + pos] = src;
    cdst[r * EE + pos] = dst;
}

// ---- N x 128 @ 128 x 128 + bias -> bf16x2 plane [N][64] uint. 4x4 register tile. ----
__global__ __launch_bounds__(256) void gemm_bf(
    const float* __restrict__ in, const float* __restrict__ W,
    const float* __restrict__ bias, unsigned* __restrict__ outp)
{
    __shared__ float As[32 * 128];    // 16 KB
    __shared__ float Ws[64 * 128];    // 32 KB (K chunked by 64)
    const int t = threadIdx.x;
    const int n0 = blockIdx.x * 32;
    for (int i = t; i < 32 * 32; i += 256) {
        int nl = i >> 5, k4 = i & 31;
        ((float4*)As)[nl * 32 + k4] = *(const float4*)(in + (size_t)(n0 + nl) * 128 + k4 * 4);
    }
    const int cg = t & 31;            // cols 4cg .. 4cg+3
    const int rg = (t >> 5) * 4;      // rows rg .. rg+3
    float4 bv = *(const float4*)(bias + 4 * cg);
    float acc[4][4];
#pragma unroll
    for (int i = 0; i < 4; ++i) {
        acc[i][0] = bv.x; acc[i][1] = bv.y; acc[i][2] = bv.z; acc[i][3] = bv.w;
    }
    for (int kc = 0; kc < 2; ++kc) {
        __syncthreads();
        for (int i = t; i < 64 * 32; i += 256) {
            int k = i >> 5, c4 = i & 31;
            ((float4*)Ws)[i] = *(const float4*)(W + (size_t)(kc * 64 + k) * 128 + c4 * 4);
        }
        __syncthreads();
        const float* Ab = As + kc * 64;
        for (int k = 0; k < 64; ++k) {
            float4 w = ((const float4*)Ws)[k * 32 + cg];
#pragma unroll
            for (int i = 0; i < 4; ++i) {
                float a = Ab[(rg + i) * 128 + k];
                acc[i][0] += a * w.x; acc[i][1] += a * w.y;
                acc[i][2] += a * w.z; acc[i][3] += a * w.w;
            }
        }
    }
#pragma unroll
    for (int i = 0; i < 4; ++i) {
        uint2 u = make_uint2(bfpack(acc[i][0], acc[i][1]), bfpack(acc[i][2], acc[i][3]));
        *(uint2*)(outp + (size_t)(n0 + rg + i) * 64 + 2 * cg) = u;
    }
}

// ---- edge scores in CSR position order ----
__global__ __launch_bounds__(256) void edge_scores_csr(
    const unsigned* __restrict__ q_bf, const unsigned* __restrict__ k_bf,
    const int* __restrict__ csrc, const int* __restrict__ cdst,
    const float* __restrict__ p4, float* __restrict__ s_out)
{
    int idx = blockIdx.x * 256 + threadIdx.x;
    if (idx >= EE * 4) return;
    int p = idx >> 2, hh = idx & 3;
    int src = csrc[p], dst = cdst[p];
    const uint4* qp = (const uint4*)(q_bf + (size_t)dst * 64 + hh * 16);
    const uint4* kp = (const uint4*)(k_bf + (size_t)src * 64 + hh * 16);
    float sum = 0.f;
#pragma unroll
    for (int i = 0; i < 4; ++i) {
        uint4 qa = qp[i], ka = kp[i];
        sum += bflo(qa.x) * bflo(ka.x) + bfhi(qa.x) * bfhi(ka.x);
        sum += bflo(qa.y) * bflo(ka.y) + bfhi(qa.y) * bfhi(ka.y);
        sum += bflo(qa.z) * bflo(ka.z) + bfhi(qa.z) * bfhi(ka.z);
        sum += bflo(qa.w) * bflo(ka.w) + bfhi(qa.w) * bfhi(ka.w);
    }
    s_out[(size_t)p * 4 + hh] = sum * p4[hh] * INV_SQRT_D;
}

// ---- CSR segment softmax (coalesced, zero indirection) ----
__global__ __launch_bounds__(256) void csr_softmax(
    float* __restrict__ s, const int* __restrict__ rp)
{
    const int dst = blockIdx.x * 4 + (threadIdx.x >> 6);
    const int lane = threadIdx.x & 63;
    const int sub = lane >> 2, hh = lane & 3;
    int beg[3], end[3];
#pragma unroll
    for (int r = 0; r < 3; ++r) {
        beg[r] = rp[r * SCAN_L + dst];
        end[r] = rp[r * SCAN_L + dst + 1];
    }
    float m = -INFINITY;
#pragma unroll
    for (int r = 0; r < 3; ++r)
        for (int p = beg[r] + sub; p < end[r]; p += 16)
            m = fmaxf(m, s[((size_t)r * EE + p) * 4 + hh]);
#pragma unroll
    for (int st = 4; st < 64; st <<= 1) m = fmaxf(m, __shfl_xor(m, st));
    float zz = 0.f;
#pragma unroll
    for (int r = 0; r < 3; ++r)
        for (int p = beg[r] + sub; p < end[r]; p += 16) {
            size_t off = ((size_t)r * EE + p) * 4 + hh;
            float ex = expf(s[off] - m);
            s[off] = ex;
            zz += ex;
        }
#pragma unroll
    for (int st = 4; st < 64; st <<= 1) zz += __shfl_xor(zz, st);
    float inv = 1.f / (zz + 1e-16f);
#pragma unroll
    for (int r = 0; r < 3; ++r)
        for (int p = beg[r] + sub; p < end[r]; p += 16)
            s[((size_t)r * EE + p) * 4 + hh] *= inv;
}

// ---- agg_v: edge-parallel CSR aggregation (LDS f32 atomics) + Wv_rel + gelu -> As bf16
// 8 dsts/block. LDS: WrelB (12 mats, pitch 528) 25344B | A [8][3][132] f32 12672B.
// __launch_bounds__(256,4): cap VGPR<=128 -> 4 waves/SIMD (R7 compiled at 248 VGPR ->
// 2 waves/SIMD -> 11.5% occupancy; this kernel is pure gather-latency-bound).
__global__ __launch_bounds__(256, 4) void agg_v(
    const unsigned* __restrict__ v_bf, const float* __restrict__ s,
    const int* __restrict__ rp, const int* __restrict__ csrc,
    const int* __restrict__ cdst,
    const unsigned* __restrict__ WvB,    // packed [3][4][32][16] this layer
    unsigned* __restrict__ As_g)
{
    __shared__ __align__(16) char smem[38016];
    unsigned* WrelB = (unsigned*)smem;             // 12 * 528
    float*    A     = (float*)(smem + 25344);      // [8][3][132]

    const int t = threadIdx.x;
    const int n0 = blockIdx.x * 8;
    const int w = t >> 6, lane = t & 63;

    for (int i = t; i < 6144; i += 256) {
        int mat = i >> 9, off = i & 511;
        WrelB[mat * 528 + off] = WvB[i];
    }
    for (int i = t; i < 8 * 3 * 132; i += 256) A[i] = 0.f;
    __syncthreads();

    // stage 1: edge-parallel, positions strided across waves; independent iterations
    {
        const int hh = lane >> 4;
        const int pcol = 2 * lane + hh;            // padded col (pitch 33/head)
        for (int r = 0; r < 3; ++r) {
            const int rb = rp[r * SCAN_L + n0];
            const int re = rp[r * SCAN_L + n0 + 8];
            for (int p = rb + w; p < re; p += 4) {
                int src = csrc[r * EE + p];
                int dl  = cdst[r * EE + p] - n0;
                float al = s[((size_t)r * EE + p) * 4 + hh];
                unsigned v2 = v_bf[(size_t)src * 64 + lane];
                float* Ap = A + (dl * 3 + r) * 132 + pcol;
                atomicAdd(Ap,     al * bflo(v2));
                atomicAdd(Ap + 1, al * bfhi(v2));
            }
        }
    }
    __syncthreads();

    // stage 2: per-head 32x32 transforms, sum over r, gelu, pack -> As_g
    // row-at-a-time + partial unroll to keep live registers low.
    {
        const int pi = t & 63, fh = pi >> 4, fq = pi & 15;
        const int rg = (t >> 6) * 2;               // rows rg, rg+1
        for (int i = 0; i < 2; ++i) {
            float o0 = 0.f, o1 = 0.f;
            for (int r = 0; r < 3; ++r) {
                const float* Ar = A + ((rg + i) * 3 + r) * 132 + fh * 33;
                const unsigned* Wp = WrelB + (r * 4 + fh) * 528 + fq;
#pragma unroll 8
                for (int d = 0; d < 32; ++d) {
                    unsigned ww = Wp[d * 16];
                    float a = Ar[d];
                    o0 += a * bflo(ww);
                    o1 += a * bfhi(ww);
                }
            }
            As_g[(size_t)(n0 + rg + i) * 64 + fh * 16 + fq] =
                bfpack(gelu_exact(o0), gelu_exact(o1));
        }
    }
}

// ---- out_ln: As(bf16) @ Wout + bout -> skip -> LayerNorm -> h. 32 rows/block, 4x4 tile ----
__global__ __launch_bounds__(256) void out_ln(
    const unsigned* __restrict__ As_g, float* __restrict__ h,
    const float* __restrict__ Wout, const float* __restrict__ bout,
    const float* __restrict__ skipp, const float* __restrict__ lg,
    const float* __restrict__ lb)
{
    __shared__ float Asl[32 * 130];   // 16640 B (padded pitch 130)
    __shared__ float Ws[64 * 128];    // 32768 B
    const int t = threadIdx.x;
    const int n0 = blockIdx.x * 32;
    for (int i = t; i < 32 * 64; i += 256) {
        int row = i >> 6, j = i & 63;
        unsigned u = As_g[(size_t)(n0 + row) * 64 + j];
        Asl[row * 130 + 2 * j]     = bflo(u);
        Asl[row * 130 + 2 * j + 1] = bfhi(u);
    }
    const int cg = t & 31;            // cols 4cg..4cg+3
    const int rg = (t >> 5) * 4;      // rows rg..rg+3
    float4 bv = *(const float4*)(bout + 4 * cg);
    float acc[4][4];
#pragma unroll
    for (int i = 0; i < 4; ++i) {
        acc[i][0] = bv.x; acc[i][1] = bv.y; acc[i][2] = bv.z; acc[i][3] = bv.w;
    }
    for (int kc = 0; kc < 2; ++kc) {
        __syncthreads();
        for (int i = t; i < 64 * 32; i += 256) {
            int k = i >> 5, c4 = i & 31;
            ((float4*)Ws)[i] = *(const float4*)(Wout + (size_t)(kc * 64 + k) * 128 + c4 * 4);
        }
        __syncthreads();
        for (int k = 0; k < 64; ++k) {
            float4 w = ((const float4*)Ws)[k * 32 + cg];
#pragma unroll
            for (int i = 0; i < 4; ++i) {
                float a = Asl[(rg + i) * 130 + kc * 64 + k];
                acc[i][0] += a * w.x; acc[i][1] += a * w.y;
                acc[i][2] += a * w.z; acc[i][3] += a * w.w;
            }
        }
    }
    const float alpha = 1.f / (1.f + expf(-skipp[0]));
    const float om = 1.f - alpha;
    float4 g4 = *(const float4*)(lg + 4 * cg);
    float4 b4 = *(const float4*)(lb + 4 * cg);
#pragma unroll
    for (int i = 0; i < 4; ++i) {
        const size_t n = (size_t)(n0 + rg + i);
        float4 hv = *(const float4*)(h + n * 128 + 4 * cg);
        float o0 = alpha * acc[i][0] + om * hv.x;
        float o1 = alpha * acc[i][1] + om * hv.y;
        float o2 = alpha * acc[i][2] + om * hv.z;
        float o3 = alpha * acc[i][3] + om * hv.w;
        float sm = o0 + o1 + o2 + o3;
#pragma unroll
        for (int m = 1; m < 32; m <<= 1) sm += __shfl_xor(sm, m);
        float mu = sm * (1.f / 128.f);
        float d0 = o0 - mu, d1 = o1 - mu, d2 = o2 - mu, d3 = o3 - mu;
        float sq = d0 * d0 + d1 * d1 + d2 * d2 + d3 * d3;
#pragma unroll
        for (int m = 1; m < 32; m <<= 1) sq += __shfl_xor(sq, m);
        float rs = rsqrtf(sq * (1.f / 128.f) + 1e-5f);
        float4 o = make_float4(d0 * rs * g4.x + b4.x, d1 * rs * g4.y + b4.y,
                               d2 * rs * g4.z + b4.z, d3 * rs * g4.w + b4.w);
        *(float4*)(h + n * 128 + 4 * cg) = o;
    }
}

// ---- parallel masked mean-pool partials (batch sorted -> run-flush) ----
__global__ __launch_bounds__(256) void pool_partial(
    const float* __restrict__ h, const float* __restrict__ x,
    const int* __restrict__ batch, float* __restrict__ psum, float* __restrict__ pcnt)
{
    const int c = threadIdx.x & 127;
    const int n0 = blockIdx.x * 64 + (threadIdx.x >> 7) * 32;
    int g = batch[n0];
    float sw = 0.f, sn = 0.f, cw = 0.f, cn = 0.f;
    for (int i = 0; i < 32; ++i) {
        int n = n0 + i;
        int gn = batch[n];
        if (gn != g) {
            atomicAdd(&psum[g * 256 + c], sw);
            atomicAdd(&psum[g * 256 + 128 + c], sn);
            if (c == 0) { atomicAdd(&pcnt[g * 2], cw); atomicAdd(&pcnt[g * 2 + 1], cn); }
            sw = sn = cw = cn = 0.f;
            g = gn;
        }
        float w = (x[(size_t)n * 5 + 1] > 0.f) ? 1.f : 0.f;
        float hv = h[(size_t)n * 128 + c];
        sw += w * hv; sn += (1.f - w) * hv;
        cw += w; cn += 1.f - w;
    }
    atomicAdd(&psum[g * 256 + c], sw);
    atomicAdd(&psum[g * 256 + 128 + c], sn);
    if (c == 0) { atomicAdd(&pcnt[g * 2], cw); atomicAdd(&pcnt[g * 2 + 1], cn); }
}

// ---------------- MLP head (pool finalize fused) ----------------
__global__ __launch_bounds__(256) void head_kernel(
    const float* __restrict__ psum, const float* __restrict__ pcnt,
    const float* __restrict__ task,
    const float* __restrict__ Wtf, const float* __restrict__ btf,
    const float* __restrict__ Wc1, const float* __restrict__ bc1,
    const float* __restrict__ Wc2, const float* __restrict__ bc2,
    float* __restrict__ out)
{
    __shared__ float in_s[640];
    __shared__ float ge_s[256];
    __shared__ float hc_s[64];
    const int b = blockIdx.x, t = threadIdx.x;
    if (t < 256) {
        float cnt = pcnt[b * 2 + (t >> 7)];
        float sv = psum[b * 256 + t];
        in_s[t] = (cnt > 0.f) ? sv / fmaxf(cnt, 1.f) : 0.f;
    }
    for (int i = t; i < 384; i += 256) in_s[256 + i] = task[b * 384 + i];
    __syncthreads();
    float acc = btf[t];
    for (int i = 0; i < 640; ++i) acc += in_s[i] * Wtf[i * 256 + t];
    ge_s[t] = fmaxf(acc, 0.f);
    __syncthreads();
    if (t < 64) {
        float a2 = bc1[t];
        for (int i = 0; i < 256; ++i) a2 += ge_s[i] * Wc1[i * 64 + t];
        hc_s[t] = fmaxf(a2, 0.f);
    }
    __syncthreads();
    if (t < 64) {
        float v = hc_s[t] * Wc2[t];
#pragma unroll
        for (int off = 32; off >= 1; off >>= 1) v += __shfl_down(v, off);
        if (t == 0) out[b] = v + bc2[0];
    }
}

__global__ __launch_bounds__(256) void zero_kernel(float4* __restrict__ p, int count4)
{
    int i = blockIdx.x * 256 + threadIdx.x;
    if (i < count4) p[i] = make_float4(0.f, 0.f, 0.f, 0.f);
}

extern "C" void kernel_launch(void* const* d_in, const int* in_sizes, int n_in,
                              void* d_out, int out_size, void* d_ws, size_t ws_size,
                              hipStream_t stream)
{
    const float* x      = (const float*)d_in[0];
    const int*   ast    = (const int*)d_in[1];
    const int*   batch  = (const int*)d_in[2];
    const int*   ei[3]  = {(const int*)d_in[3], (const int*)d_in[4], (const int*)d_in[5]};
    const float* task   = (const float*)d_in[6];
    const float* emb    = (const float*)d_in[7];
    const float* Win    = (const float*)d_in[8];
    const float* bin_   = (const float*)d_in[9];
    const float* Wkqv   = (const float*)d_in[10];
    const float* bkqv   = (const float*)d_in[11];
    const float* Wk_rel = (const float*)d_in[12];
    const float* Wv_rel = (const float*)d_in[13];
    const float* p_rel  = (const float*)d_in[14];
    const float* Wout   = (const float*)d_in[15];
    const float* bout   = (const float*)d_in[16];
    const float* skip   = (const float*)d_in[17];
    const float* ln_g   = (const float*)d_in[18];
    const float* ln_b   = (const float*)d_in[19];
    const float* Wtf    = (const float*)d_in[20];
    const float* btf    = (const float*)d_in[21];
    const float* Wc1    = (const float*)d_in[22];
    const float* bc1    = (const float*)d_in[23];
    const float* Wc2    = (const float*)d_in[24];
    const float* bc2    = (const float*)d_in[25];
    float* out = (float*)d_out;
    float* ws  = (float*)d_ws;

    float*    h    = ws + OFF_H;
    unsigned* PQ   = (unsigned*)(ws + OFF_PQ);   // q plane, then v_base plane
    unsigned* PK   = (unsigned*)(ws + OFF_PK);   // kt_r plane, then As plane
    float*    sbuf = ws + OFF_S;
    int*      rp   = (int*)(ws + OFF_RP);
    int*      csrc = (int*)(ws + OFF_CSRC);
    int*      cdst = (int*)(ws + OFF_CDST);
    int*      fill = (int*)(ws + OFF_PQ);        // aliases PQ during CSR build only
    float*    Wf   = ws + OFF_WF;
    float*    bf   = ws + OFF_BF;
    int*      bs   = (int*)(ws + OFF_BS);
    float*    psum = ws + OFF_POOL;
    float*    pcnt = psum + (size_t)BB * 256;
    unsigned* WvB  = (unsigned*)(ws + OFF_WVB);

    fold_weights<<<10, 256, 0, stream>>>(Wkqv, bkqv, Wk_rel, Wf, bf);
    pack_wv<<<48, 256, 0, stream>>>(Wv_rel, WvB);
    input_proj<<<NN / 16, 256, 0, stream>>>(x, ast, emb, Win, bin_, h);

    zero_kernel<<<(600016 / 4 + 255) / 256, 256, 0, stream>>>((float4*)rp, 600016 / 4);
    zero_kernel<<<(600000 / 4 + 255) / 256, 256, 0, stream>>>((float4*)fill, 600000 / 4);
    csr_hist<<<(3 * EE + 255) / 256, 256, 0, stream>>>(ei[0], ei[1], ei[2], rp);
    scan1<<<dim3(SCAN_NB, 3), 256, 0, stream>>>(rp, bs);
    scan2<<<3, 128, 0, stream>>>(bs);
    scan3<<<dim3(SCAN_NB, 3), 256, 0, stream>>>(rp, bs);
    csr_scatter<<<(3 * EE + 255) / 256, 256, 0, stream>>>(
        ei[0], ei[1], ei[2], rp, fill, csrc, cdst);

    for (int l = 0; l < 2; ++l) {
        const size_t ls = (size_t)l * 5;   // slots: 0=q, 1..3=k_r, 4=v
        gemm_bf<<<NN / 32, 256, 0, stream>>>(h, Wf + ls * 16384, bf + ls * 128, PQ);
        for (int r = 0; r < 3; ++r) {
            gemm_bf<<<NN / 32, 256, 0, stream>>>(
                h, Wf + (ls + 1 + r) * 16384, bf + (ls + 1 + r) * 128, PK);
            edge_scores_csr<<<(EE * 4 + 255) / 256, 256, 0, stream>>>(
                PQ, PK, csrc + (size_t)r * EE, cdst + (size_t)r * EE,
                p_rel + (size_t)(l * 3 + r) * 4, sbuf + (size_t)r * EE * 4);
        }
        csr_softmax<<<NN / 4, 256, 0, stream>>>(sbuf, rp);
        // q dead -> PQ becomes v_base; kt dead -> PK becomes As plane
        gemm_bf<<<NN / 32, 256, 0, stream>>>(h, Wf + (ls + 4) * 16384, bf + (ls + 4) * 128, PQ);
        agg_v<<<NN / 8, 256, 0, stream>>>(
            PQ, sbuf, rp, csrc, cdst, WvB + (size_t)l * 6144, PK);
        out_ln<<<NN / 32, 256, 0, stream>>>(
            PK, h, Wout + (size_t)l * 16384, bout + (size_t)l * 128,
            skip + l, ln_g + (size_t)l * 128, ln_b + (size_t)l * 128);
    }

    zero_kernel<<<(16512 / 4 + 255) / 256, 256, 0, stream>>>((float4*)psum, 16512 / 4);
    pool_partial<<<NN / 64, 256, 0, stream>>>(h, x, batch, psum, pcnt);
    head_kernel<<<BB, 256, 0, stream>>>(psum, pcnt, task, Wtf, btf, Wc1, bc1, Wc2, bc2, out);
}

// Round 9
// 3337.578 us; speedup vs baseline: 1.7417x; 1.0480x over previous
//
#include <hip/hip_runtime.h>
#include <math.h>

// Problem constants (match reference)
#define NN 200000
#define EE 300000
#define BB 64
#define INV_SQRT_D 0.17677669529663687f

// ---- workspace layout in 4-byte words. Total ≈ 57.4M words = 229.6 MB.
// ws budget is ~256MB-class (252 passed, 329 faulted) -> stay <= 252 MB.
#define OFF_H    ((size_t)0)                    // [N][128] f32 node features
#define OFF_PQ   ((size_t)25600000)             // [N][64] uint (bf16x2): q, then v_base
#define OFF_PK   ((size_t)38400000)             // [N][64] uint (bf16x2): kt_r, then As plane
#define OFF_S    ((size_t)51200000)             // [3][E][4] f32 scores -> alpha (CSR order)
#define OFF_RP   ((size_t)54800000)             // [3][N+1] int rowptr (padded 600016)
#define OFF_CSRC ((size_t)55400016)             // [3][E] int src per CSR position
#define OFF_CDST ((size_t)56300016)             // [3][E] int dst per CSR position
#define OFF_WF   ((size_t)57200016)             // 10 x [128][128] f32 folded weights
#define OFF_BF   ((size_t)57363856)             // 10 x [128] f32 folded bias
#define OFF_BS   ((size_t)57365136)             // scan block sums 3*128 int
#define OFF_POOL ((size_t)57365520)             // psum [B][256] + pcnt [B][2] (16512)
#define OFF_WVB  ((size_t)57382032)             // 2 x 6144 uint packed Wv_rel

#define SCAN_L   (NN + 1)
#define SCAN_E   8
#define SCAN_EPB (256 * SCAN_E)                          // 2048
#define SCAN_NB  ((SCAN_L + SCAN_EPB - 1) / SCAN_EPB)    // 98

__device__ __forceinline__ float gelu_exact(float v) {
    return 0.5f * v * (1.0f + erff(v * 0.70710678118654752f));
}
__device__ __forceinline__ float bflo(unsigned u) { return __uint_as_float(u << 16); }
__device__ __forceinline__ float bfhi(unsigned u) { return __uint_as_float(u & 0xffff0000u); }
__device__ __forceinline__ unsigned bfpack(float a, float b) {
    unsigned ua = __float_as_uint(a); ua += 0x7fffu + ((ua >> 16) & 1u);
    unsigned ub = __float_as_uint(b); ub += 0x7fffu + ((ub >> 16) & 1u);
    return (ua >> 16) | (ub & 0xffff0000u);
}

// ---- fold weights. 10 slots: per layer l: [l*5+0]=q copy, [l*5+1+r]=k@Wk_rel[r], [l*5+4]=v copy
__global__ __launch_bounds__(256) void fold_weights(
    const float* __restrict__ Wkqv, const float* __restrict__ bkqv,
    const float* __restrict__ Wk_rel,
    float* __restrict__ Wf, float* __restrict__ bf)
{
    __shared__ float Wr[4096];
    const int b = blockIdx.x, t = threadIdx.x;
    const int l = b / 5, s = b % 5;
    const float* Wq = Wkqv + (size_t)l * 49152;   // [128][384]
    if (s == 0 || s == 4) {
        const int off = (s == 0) ? 128 : 256;
        for (int i = t; i < 16384; i += 256) {
            int kk = i >> 7, c = i & 127;
            Wf[(size_t)b * 16384 + i] = Wq[kk * 384 + off + c];
        }
        if (t < 128) bf[b * 128 + t] = bkqv[l * 384 + off + t];
    } else {
        const int r = s - 1;
        const float* Wrel = Wk_rel + (size_t)(l * 3 + r) * 4096;
        for (int i = t; i < 4096; i += 256) Wr[i] = Wrel[i];
        __syncthreads();
        for (int i = t; i < 16384; i += 256) {
            int kk = i >> 7, c = i & 127, hh = c >> 5, f = c & 31;
            const float* wrow = Wq + kk * 384 + hh * 32;   // k block (cols 0..127)
            const float* wr = Wr + hh * 1024 + f;
            float sum = 0.f;
#pragma unroll
            for (int d = 0; d < 32; ++d) sum += wrow[d] * wr[d * 32];
            Wf[(size_t)b * 16384 + i] = sum;
        }
        if (t < 128) {
            int hh = t >> 5, f = t & 31;
            float sum = 0.f;
#pragma unroll
            for (int d = 0; d < 32; ++d)
                sum += bkqv[l * 384 + hh * 32 + d] * Wr[hh * 1024 + d * 32 + f];
            bf[b * 128 + t] = sum;
        }
    }
}

// ---- pack Wv_rel (both layers) to bf16x2 once per call ----
__global__ __launch_bounds__(256) void pack_wv(
    const float* __restrict__ Wv_rel, unsigned* __restrict__ WvB)
{
    int i = blockIdx.x * 256 + threadIdx.x;
    if (i < 12288) WvB[i] = bfpack(Wv_rel[2 * i], Wv_rel[2 * i + 1]);
}

// ---------------- input projection: h = [emb[ast], x] @ Win + bin ----------------
__global__ __launch_bounds__(256) void input_proj(
    const float* __restrict__ x, const int* __restrict__ ast,
    const float* __restrict__ emb, const float* __restrict__ Win,
    const float* __restrict__ bin_, float* __restrict__ h)
{
    __shared__ float Ws[69 * 128];
    __shared__ float As[16 * 70];
    const int t = threadIdx.x;
    const int n0 = blockIdx.x * 16;
    for (int i = t; i < 69 * 128; i += 256) Ws[i] = Win[i];
    for (int i = t; i < 16 * 69; i += 256) {
        int nl = i / 69, kk = i - nl * 69;
        int n = n0 + nl;
        float v = (kk < 64) ? emb[ast[n] * 64 + kk] : x[n * 5 + (kk - 64)];
        As[nl * 70 + kk] = v;
    }
    __syncthreads();
    const int c = t & 127;
    const int nh = (t >> 7) * 8;
    float acc[8];
    float bv = bin_[c];
#pragma unroll
    for (int j = 0; j < 8; ++j) acc[j] = bv;
    for (int k = 0; k < 69; ++k) {
        float w = Ws[k * 128 + c];
#pragma unroll
        for (int j = 0; j < 8; ++j) acc[j] += As[(nh + j) * 70 + k] * w;
    }
#pragma unroll
    for (int j = 0; j < 8; ++j) h[(size_t)(n0 + nh + j) * 128 + c] = acc[j];
}

// ---- CSR build: histogram -> scan -> scatter ----
__global__ __launch_bounds__(256) void csr_hist(
    const int* __restrict__ ei0, const int* __restrict__ ei1, const int* __restrict__ ei2,
    int* __restrict__ rp)
{
    int idx = blockIdx.x * 256 + threadIdx.x;
    if (idx >= 3 * EE) return;
    int r = idx / EE, e = idx - r * EE;
    const int* ei = (r == 0) ? ei0 : ((r == 1) ? ei1 : ei2);
    atomicAdd(&rp[r * SCAN_L + ei[EE + e] + 1], 1);
}

__global__ __launch_bounds__(256) void scan1(int* __restrict__ rp, int* __restrict__ bs)
{
    __shared__ int ts[256];
    const int r = blockIdx.y;
    int* a = rp + (size_t)r * SCAN_L;
    const int base = blockIdx.x * SCAN_EPB + threadIdx.x * SCAN_E;
    int v[SCAN_E];
    int tot = 0;
#pragma unroll
    for (int j = 0; j < SCAN_E; ++j) {
        int idx = base + j;
        v[j] = (idx < SCAN_L) ? a[idx] : 0;
        tot += v[j];
    }
    ts[threadIdx.x] = tot;
    __syncthreads();
    for (int st = 1; st < 256; st <<= 1) {
        int add = (threadIdx.x >= st) ? ts[threadIdx.x - st] : 0;
        __syncthreads();
        ts[threadIdx.x] += add;
        __syncthreads();
    }
    int run = ts[threadIdx.x] - tot;
#pragma unroll
    for (int j = 0; j < SCAN_E; ++j) {
        run += v[j];
        int idx = base + j;
        if (idx < SCAN_L) a[idx] = run;
    }
    if (threadIdx.x == 255) bs[r * 128 + blockIdx.x] = ts[255];
}

__global__ __launch_bounds__(128) void scan2(int* __restrict__ bs)
{
    __shared__ int ts[128];
    const int r = blockIdx.x, t = threadIdx.x;
    int v = (t < SCAN_NB) ? bs[r * 128 + t] : 0;
    ts[t] = v;
    __syncthreads();
    for (int st = 1; st < 128; st <<= 1) {
        int add = (t >= st) ? ts[t - st] : 0;
        __syncthreads();
        ts[t] += add;
        __syncthreads();
    }
    bs[r * 128 + t] = ts[t];
}

__global__ __launch_bounds__(256) void scan3(int* __restrict__ rp, const int* __restrict__ bs)
{
    const int r = blockIdx.y;
    if (blockIdx.x == 0) return;
    const int off = bs[r * 128 + blockIdx.x - 1];
    const int base = blockIdx.x * SCAN_EPB + threadIdx.x * SCAN_E;
    int* a = rp + (size_t)r * SCAN_L;
#pragma unroll
    for (int j = 0; j < SCAN_E; ++j) {
        int idx = base + j;
        if (idx < SCAN_L) a[idx] += off;
    }
}

__global__ __launch_bounds__(256) void csr_scatter(
    const int* __restrict__ ei0, const int* __restrict__ ei1, const int* __restrict__ ei2,
    const int* __restrict__ rp, int* __restrict__ fill,
    int* __restrict__ csrc, int* __restrict__ cdst)
{
    int idx = blockIdx.x * 256 + threadIdx.x;
    if (idx >= 3 * EE) return;
    int r = idx / EE, e = idx - r * EE;
    const int* ei = (r == 0) ? ei0 : ((r == 1) ? ei1 : ei2);
    int src = ei[e], dst = ei[EE + e];
    int pos = rp[r * SCAN_L + dst] + atomicAdd(&fill[r * NN + dst], 1);
    csrc[r * EE + pos] = src;
    cdst[r * EE + pos] = dst;
}

// ---- N x 128 @ 128 x 128 + bias -> bf16x2 plane [N][64] uint. 4x4 register tile. ----
__global__ __launch_bounds__(256) void gemm_bf(
    const float* __restrict__ in, const float* __restrict__ W,
    const float* __restrict__ bias, unsigned* __restrict__ outp)
{
    __shared__ float As[32 * 128];    // 16 KB
    __shared__ float Ws[64 * 128];    // 32 KB (K chunked by 64)
    const int t = threadIdx.x;
    const int n0 = blockIdx.x * 32;
    for (int i = t; i < 32 * 32; i += 256) {
        int nl = i >> 5, k4 = i & 31;
        ((float4*)As)[nl * 32 + k4] = *(const float4*)(in + (size_t)(n0 + nl) * 128 + k4 * 4);
    }
    const int cg = t & 31;            // cols 4cg .. 4cg+3
    const int rg = (t >> 5) * 4;      // rows rg .. rg+3
    float4 bv = *(const float4*)(bias + 4 * cg);
    float acc[4][4];
#pragma unroll
    for (int i = 0; i < 4; ++i) {
        acc[i][0] = bv.x; acc[i][1] = bv.y; acc[i][2] = bv.z; acc[i][3] = bv.w;
    }
    for (int kc = 0; kc < 2; ++kc) {
        __syncthreads();
        for (int i = t; i < 64 * 32; i += 256) {
            int k = i >> 5, c4 = i & 31;
            ((float4*)Ws)[i] = *(const float4*)(W + (size_t)(kc * 64 + k) * 128 + c4 * 4);
        }
        __syncthreads();
        const float* Ab = As + kc * 64;
        for (int k = 0; k < 64; ++k) {
            float4 w = ((const float4*)Ws)[k * 32 + cg];
#pragma unroll
            for (int i = 0; i < 4; ++i) {
                float a = Ab[(rg + i) * 128 + k];
                acc[i][0] += a * w.x; acc[i][1] += a * w.y;
                acc[i][2] += a * w.z; acc[i][3] += a * w.w;
            }
        }
    }
#pragma unroll
    for (int i = 0; i < 4; ++i) {
        uint2 u = make_uint2(bfpack(acc[i][0], acc[i][1]), bfpack(acc[i][2], acc[i][3]));
        *(uint2*)(outp + (size_t)(n0 + rg + i) * 64 + 2 * cg) = u;
    }
}

// ---- edge scores in CSR position order (one relation per dispatch) ----
__global__ __launch_bounds__(256) void edge_scores_csr(
    const unsigned* __restrict__ q_bf, const unsigned* __restrict__ k_bf,
    const int* __restrict__ csrc, const int* __restrict__ cdst,
    const float* __restrict__ p4, float* __restrict__ s_out)
{
    int idx = blockIdx.x * 256 + threadIdx.x;
    if (idx >= EE * 4) return;
    int p = idx >> 2, hh = idx & 3;
    int src = csrc[p], dst = cdst[p];
    const uint4* qp = (const uint4*)(q_bf + (size_t)dst * 64 + hh * 16);
    const uint4* kp = (const uint4*)(k_bf + (size_t)src * 64 + hh * 16);
    float sum = 0.f;
#pragma unroll
    for (int i = 0; i < 4; ++i) {
        uint4 qa = qp[i], ka = kp[i];
        sum += bflo(qa.x) * bflo(ka.x) + bfhi(qa.x) * bfhi(ka.x);
        sum += bflo(qa.y) * bflo(ka.y) + bfhi(qa.y) * bfhi(ka.y);
        sum += bflo(qa.z) * bflo(ka.z) + bfhi(qa.z) * bfhi(ka.z);
        sum += bflo(qa.w) * bflo(ka.w) + bfhi(qa.w) * bfhi(ka.w);
    }
    s_out[(size_t)p * 4 + hh] = sum * p4[hh] * INV_SQRT_D;
}

// ---- CSR segment softmax (coalesced, zero indirection) ----
__global__ __launch_bounds__(256) void csr_softmax(
    float* __restrict__ s, const int* __restrict__ rp)
{
    const int dst = blockIdx.x * 4 + (threadIdx.x >> 6);
    const int lane = threadIdx.x & 63;
    const int sub = lane >> 2, hh = lane & 3;
    int beg[3], end[3];
#pragma unroll
    for (int r = 0; r < 3; ++r) {
        beg[r] = rp[r * SCAN_L + dst];
        end[r] = rp[r * SCAN_L + dst + 1];
    }
    float m = -INFINITY;
#pragma unroll
    for (int r = 0; r < 3; ++r)
        for (int p = beg[r] + sub; p < end[r]; p += 16)
            m = fmaxf(m, s[((size_t)r * EE + p) * 4 + hh]);
#pragma unroll
    for (int st = 4; st < 64; st <<= 1) m = fmaxf(m, __shfl_xor(m, st));
    float zz = 0.f;
#pragma unroll
    for (int r = 0; r < 3; ++r)
        for (int p = beg[r] + sub; p < end[r]; p += 16) {
            size_t off = ((size_t)r * EE + p) * 4 + hh;
            float ex = expf(s[off] - m);
            s[off] = ex;
            zz += ex;
        }
#pragma unroll
    for (int st = 4; st < 64; st <<= 1) zz += __shfl_xor(zz, st);
    float inv = 1.f / (zz + 1e-16f);
#pragma unroll
    for (int r = 0; r < 3; ++r)
        for (int p = beg[r] + sub; p < end[r]; p += 16)
            s[((size_t)r * EE + p) * 4 + hh] *= inv;
}

// ---- agg_v: edge-parallel CSR aggregation (LDS f32 atomics) + Wv_rel + gelu -> As bf16
// 8 dsts/block. LDS = A only (12672 B) -> 8 blocks/CU (32-wave cap); Wv_rel read
// from global (24 KB table shared by all blocks -> L1/L2 resident).
// __launch_bounds__(256,8): VGPR<=64 (R8 compiled at 52 -> fits).
// Stage-1 gather loop 2-wide software-pipelined (2 v_bf gathers in flight/wave).
__global__ __launch_bounds__(256, 8) void agg_v(
    const unsigned* __restrict__ v_bf, const float* __restrict__ s,
    const int* __restrict__ rp, const int* __restrict__ csrc,
    const int* __restrict__ cdst,
    const unsigned* __restrict__ WvB,    // packed [3][4][32][16] this layer
    unsigned* __restrict__ As_g)
{
    __shared__ float A[8 * 3 * 132];               // 12672 B

    const int t = threadIdx.x;
    const int n0 = blockIdx.x * 8;
    const int w = t >> 6, lane = t & 63;

    for (int i = t; i < 8 * 3 * 132; i += 256) A[i] = 0.f;
    __syncthreads();

    // stage 1: edge-parallel, positions strided across waves; 2-wide pipeline
    {
        const int hh = lane >> 4;
        const int pcol = 2 * lane + hh;            // padded col (pitch 33/head)
        for (int r = 0; r < 3; ++r) {
            const int rb = rp[r * SCAN_L + n0];
            const int re = rp[r * SCAN_L + n0 + 8];
            int p = rb + w;
            for (; p + 4 < re; p += 8) {
                int src0 = csrc[r * EE + p];
                int dl0  = cdst[r * EE + p] - n0;
                float al0 = s[((size_t)r * EE + p) * 4 + hh];
                int p1 = p + 4;
                int src1 = csrc[r * EE + p1];
                int dl1  = cdst[r * EE + p1] - n0;
                float al1 = s[((size_t)r * EE + p1) * 4 + hh];
                unsigned v0 = v_bf[(size_t)src0 * 64 + lane];
                unsigned v1 = v_bf[(size_t)src1 * 64 + lane];
                float* A0 = A + (dl0 * 3 + r) * 132 + pcol;
                atomicAdd(A0,     al0 * bflo(v0));
                atomicAdd(A0 + 1, al0 * bfhi(v0));
                float* A1 = A + (dl1 * 3 + r) * 132 + pcol;
                atomicAdd(A1,     al1 * bflo(v1));
                atomicAdd(A1 + 1, al1 * bfhi(v1));
            }
            for (; p < re; p += 4) {
                int src = csrc[r * EE + p];
                int dl  = cdst[r * EE + p] - n0;
                float al = s[((size_t)r * EE + p) * 4 + hh];
                unsigned v2 = v_bf[(size_t)src * 64 + lane];
                float* Ap = A + (dl * 3 + r) * 132 + pcol;
                atomicAdd(Ap,     al * bflo(v2));
                atomicAdd(Ap + 1, al * bfhi(v2));
            }
        }
    }
    __syncthreads();

    // stage 2: per-head 32x32 transforms (W from global, L1-hot), sum over r, gelu
    {
        const int pi = t & 63, fh = pi >> 4, fq = pi & 15;
        const int rg = (t >> 6) * 2;               // rows rg, rg+1
        for (int i = 0; i < 2; ++i) {
            float o0 = 0.f, o1 = 0.f;
            for (int r = 0; r < 3; ++r) {
                const float* Ar = A + ((rg + i) * 3 + r) * 132 + fh * 33;
                const unsigned* Wp = WvB + (r * 4 + fh) * 512 + fq;
#pragma unroll 8
                for (int d = 0; d < 32; ++d) {
                    unsigned ww = Wp[d * 16];
                    float a = Ar[d];
                    o0 += a * bflo(ww);
                    o1 += a * bfhi(ww);
                }
            }
            As_g[(size_t)(n0 + rg + i) * 64 + fh * 16 + fq] =
                bfpack(gelu_exact(o0), gelu_exact(o1));
        }
    }
}

// ---- out_ln: As(bf16) @ Wout + bout -> skip -> LayerNorm -> h. 32 rows/block, 4x4 tile ----
__global__ __launch_bounds__(256) void out_ln(
    const unsigned* __restrict__ As_g, float* __restrict__ h,
    const float* __restrict__ Wout, const float* __restrict__ bout,
    const float* __restrict__ skipp, const float* __restrict__ lg,
    const float* __restrict__ lb)
{
    __shared__ float Asl[32 * 130];   // 16640 B (padded pitch 130)
    __shared__ float Ws[64 * 128];    // 32768 B
    const int t = threadIdx.x;
    const int n0 = blockIdx.x * 32;
    for (int i = t; i < 32 * 64; i += 256) {
        int row = i >> 6, j = i & 63;
        unsigned u = As_g[(size_t)(n0 + row) * 64 + j];
        Asl[row * 130 + 2 * j]     = bflo(u);
        Asl[row * 130 + 2 * j + 1] = bfhi(u);
    }
    const int cg = t & 31;            // cols 4cg..4cg+3
    const int rg = (t >> 5) * 4;      // rows rg..rg+3
    float4 bv = *(const float4*)(bout + 4 * cg);
    float acc[4][4];
#pragma unroll
    for (int i = 0; i < 4; ++i) {
        acc[i][0] = bv.x; acc[i][1] = bv.y; acc[i][2] = bv.z; acc[i][3] = bv.w;
    }
    for (int kc = 0; kc < 2; ++kc) {
        __syncthreads();
        for (int i = t; i < 64 * 32; i += 256) {
            int k = i >> 5, c4 = i & 31;
            ((float4*)Ws)[i] = *(const float4*)(Wout + (size_t)(kc * 64 + k) * 128 + c4 * 4);
        }
        __syncthreads();
        for (int k = 0; k < 64; ++k) {
            float4 w = ((const float4*)Ws)[k * 32 + cg];
#pragma unroll
            for (int i = 0; i < 4; ++i) {
                float a = Asl[(rg + i) * 130 + kc * 64 + k];
                acc[i][0] += a * w.x; acc[i][1] += a * w.y;
                acc[i][2] += a * w.z; acc[i][3] += a * w.w;
            }
        }
    }
    const float alpha = 1.f / (1.f + expf(-skipp[0]));
    const float om = 1.f - alpha;
    float4 g4 = *(const float4*)(lg + 4 * cg);
    float4 b4 = *(const float4*)(lb + 4 * cg);
#pragma unroll
    for (int i = 0; i < 4; ++i) {
        const size_t n = (size_t)(n0 + rg + i);
        float4 hv = *(const float4*)(h + n * 128 + 4 * cg);
        float o0 = alpha * acc[i][0] + om * hv.x;
        float o1 = alpha * acc[i][1] + om * hv.y;
        float o2 = alpha * acc[i][2] + om * hv.z;
        float o3 = alpha * acc[i][3] + om * hv.w;
        float sm = o0 + o1 + o2 + o3;
#pragma unroll
        for (int m = 1; m < 32; m <<= 1) sm += __shfl_xor(sm, m);
        float mu = sm * (1.f / 128.f);
        float d0 = o0 - mu, d1 = o1 - mu, d2 = o2 - mu, d3 = o3 - mu;
        float sq = d0 * d0 + d1 * d1 + d2 * d2 + d3 * d3;
#pragma unroll
        for (int m = 1; m < 32; m <<= 1) sq += __shfl_xor(sq, m);
        float rs = rsqrtf(sq * (1.f / 128.f) + 1e-5f);
        float4 o = make_float4(d0 * rs * g4.x + b4.x, d1 * rs * g4.y + b4.y,
                               d2 * rs * g4.z + b4.z, d3 * rs * g4.w + b4.w);
        *(float4*)(h + n * 128 + 4 * cg) = o;
    }
}

// ---- parallel masked mean-pool partials (batch sorted -> run-flush) ----
__global__ __launch_bounds__(256) void pool_partial(
    const float* __restrict__ h, const float* __restrict__ x,
    const int* __restrict__ batch, float* __restrict__ psum, float* __restrict__ pcnt)
{
    const int c = threadIdx.x & 127;
    const int n0 = blockIdx.x * 64 + (threadIdx.x >> 7) * 32;
    int g = batch[n0];
    float sw = 0.f, sn = 0.f, cw = 0.f, cn = 0.f;
    for (int i = 0; i < 32; ++i) {
        int n = n0 + i;
        int gn = batch[n];
        if (gn != g) {
            atomicAdd(&psum[g * 256 + c], sw);
            atomicAdd(&psum[g * 256 + 128 + c], sn);
            if (c == 0) { atomicAdd(&pcnt[g * 2], cw); atomicAdd(&pcnt[g * 2 + 1], cn); }
            sw = sn = cw = cn = 0.f;
            g = gn;
        }
        float w = (x[(size_t)n * 5 + 1] > 0.f) ? 1.f : 0.f;
        float hv = h[(size_t)n * 128 + c];
        sw += w * hv; sn += (1.f - w) * hv;
        cw += w; cn += 1.f - w;
    }
    atomicAdd(&psum[g * 256 + c], sw);
    atomicAdd(&psum[g * 256 + 128 + c], sn);
    if (c == 0) { atomicAdd(&pcnt[g * 2], cw); atomicAdd(&pcnt[g * 2 + 1], cn); }
}

// ---------------- MLP head (pool finalize fused) ----------------
__global__ __launch_bounds__(256) void head_kernel(
    const float* __restrict__ psum, const float* __restrict__ pcnt,
    const float* __restrict__ task,
    const float* __restrict__ Wtf, const float* __restrict__ btf,
    const float* __restrict__ Wc1, const float* __restrict__ bc1,
    const float* __restrict__ Wc2, const float* __restrict__ bc2,
    float* __restrict__ out)
{
    __shared__ float in_s[640];
    __shared__ float ge_s[256];
    __shared__ float hc_s[64];
    const int b = blockIdx.x, t = threadIdx.x;
    if (t < 256) {
        float cnt = pcnt[b * 2 + (t >> 7)];
        float sv = psum[b * 256 + t];
        in_s[t] = (cnt > 0.f) ? sv / fmaxf(cnt, 1.f) : 0.f;
    }
    for (int i = t; i < 384; i += 256) in_s[256 + i] = task[b * 384 + i];
    __syncthreads();
    float acc = btf[t];
    for (int i = 0; i < 640; ++i) acc += in_s[i] * Wtf[i * 256 + t];
    ge_s[t] = fmaxf(acc, 0.f);
    __syncthreads();
    if (t < 64) {
        float a2 = bc1[t];
        for (int i = 0; i < 256; ++i) a2 += ge_s[i] * Wc1[i * 64 + t];
        hc_s[t] = fmaxf(a2, 0.f);
    }
    __syncthreads();
    if (t < 64) {
        float v = hc_s[t] * Wc2[t];
#pragma unroll
        for (int off = 32; off >= 1; off >>= 1) v += __shfl_down(v, off);
        if (t == 0) out[b] = v + bc2[0];
    }
}

__global__ __launch_bounds__(256) void zero_kernel(float4* __restrict__ p, int count4)
{
    int i = blockIdx.x * 256 + threadIdx.x;
    if (i < count4) p[i] = make_float4(0.f, 0.f, 0.f, 0.f);
}

extern "C" void kernel_launch(void* const* d_in, const int* in_sizes, int n_in,
                              void* d_out, int out_size, void* d_ws, size_t ws_size,
                              hipStream_t stream)
{
    const float* x      = (const float*)d_in[0];
    const int*   ast    = (const int*)d_in[1];
    const int*   batch  = (const int*)d_in[2];
    const int*   ei[3]  = {(const int*)d_in[3], (const int*)d_in[4], (const int*)d_in[5]};
    const float* task   = (const float*)d_in[6];
    const float* emb    = (const float*)d_in[7];
    const float* Win    = (const float*)d_in[8];
    const float* bin_   = (const float*)d_in[9];
    const float* Wkqv   = (const float*)d_in[10];
    const float* bkqv   = (const float*)d_in[11];
    const float* Wk_rel = (const float*)d_in[12];
    const float* Wv_rel = (const float*)d_in[13];
    const float* p_rel  = (const float*)d_in[14];
    const float* Wout   = (const float*)d_in[15];
    const float* bout   = (const float*)d_in[16];
    const float* skip   = (const float*)d_in[17];
    const float* ln_g   = (const float*)d_in[18];
    const float* ln_b   = (const float*)d_in[19];
    const float* Wtf    = (const float*)d_in[20];
    const float* btf    = (const float*)d_in[21];
    const float* Wc1    = (const float*)d_in[22];
    const float* bc1    = (const float*)d_in[23];
    const float* Wc2    = (const float*)d_in[24];
    const float* bc2    = (const float*)d_in[25];
    float* out = (float*)d_out;
    float* ws  = (float*)d_ws;

    float*    h    = ws + OFF_H;
    unsigned* PQ   = (unsigned*)(ws + OFF_PQ);   // q plane, then v_base plane
    unsigned* PK   = (unsigned*)(ws + OFF_PK);   // kt_r plane, then As plane
    float*    sbuf = ws + OFF_S;
    int*      rp   = (int*)(ws + OFF_RP);
    int*      csrc = (int*)(ws + OFF_CSRC);
    int*      cdst = (int*)(ws + OFF_CDST);
    int*      fill = (int*)(ws + OFF_PQ);        // aliases PQ during CSR build only
    float*    Wf   = ws + OFF_WF;
    float*    bf   = ws + OFF_BF;
    int*      bs   = (int*)(ws + OFF_BS);
    float*    psum = ws + OFF_POOL;
    float*    pcnt = psum + (size_t)BB * 256;
    unsigned* WvB  = (unsigned*)(ws + OFF_WVB);

    fold_weights<<<10, 256, 0, stream>>>(Wkqv, bkqv, Wk_rel, Wf, bf);
    pack_wv<<<48, 256, 0, stream>>>(Wv_rel, WvB);
    input_proj<<<NN / 16, 256, 0, stream>>>(x, ast, emb, Win, bin_, h);

    zero_kernel<<<(600016 / 4 + 255) / 256, 256, 0, stream>>>((float4*)rp, 600016 / 4);
    zero_kernel<<<(600000 / 4 + 255) / 256, 256, 0, stream>>>((float4*)fill, 600000 / 4);
    csr_hist<<<(3 * EE + 255) / 256, 256, 0, stream>>>(ei[0], ei[1], ei[2], rp);
    scan1<<<dim3(SCAN_NB, 3), 256, 0, stream>>>(rp, bs);
    scan2<<<3, 128, 0, stream>>>(bs);
    scan3<<<dim3(SCAN_NB, 3), 256, 0, stream>>>(rp, bs);
    csr_scatter<<<(3 * EE + 255) / 256, 256, 0, stream>>>(
        ei[0], ei[1], ei[2], rp, fill, csrc, cdst);

    for (int l = 0; l < 2; ++l) {
        const size_t ls = (size_t)l * 5;   // slots: 0=q, 1..3=k_r, 4=v
        gemm_bf<<<NN / 32, 256, 0, stream>>>(h, Wf + ls * 16384, bf + ls * 128, PQ);
        for (int r = 0; r < 3; ++r) {
            gemm_bf<<<NN / 32, 256, 0, stream>>>(
                h, Wf + (ls + 1 + r) * 16384, bf + (ls + 1 + r) * 128, PK);
            edge_scores_csr<<<(EE * 4 + 255) / 256, 256, 0, stream>>>(
                PQ, PK, csrc + (size_t)r * EE, cdst + (size_t)r * EE,
                p_rel + (size_t)(l * 3 + r) * 4, sbuf + (size_t)r * EE * 4);
        }
        csr_softmax<<<NN / 4, 256, 0, stream>>>(sbuf, rp);
        // q dead -> PQ becomes v_base; kt dead -> PK becomes As plane
        gemm_bf<<<NN / 32, 256, 0, stream>>>(h, Wf + (ls + 4) * 16384, bf + (ls + 4) * 128, PQ);
        agg_v<<<NN / 8, 256, 0, stream>>>(
            PQ, sbuf, rp, csrc, cdst, WvB + (size_t)l * 6144, PK);
        out_ln<<<NN / 32, 256, 0, stream>>>(
            PK, h, Wout + (size_t)l * 16384, bout + (size_t)l * 128,
            skip + l, ln_g + (size_t)l * 128, ln_b + (size_t)l * 128);
    }

    zero_kernel<<<(16512 / 4 + 255) / 256, 256, 0, stream>>>((float4*)psum, 16512 / 4);
    pool_partial<<<NN / 64, 256, 0, stream>>>(h, x, batch, psum, pcnt);
    head_kernel<<<BB, 256, 0, stream>>>(psum, pcnt, task, Wtf, btf, Wc1, bc1, Wc2, bc2, out);
}